// Round 8
// baseline (555.436 us; speedup 1.0000x reference)
//
#include <hip/hip_runtime.h>
#include <math.h>

#define DIMC 384
#define NHD 8
#define NSTATE 16
#define DINN 768
#define DTRK 24
#define BB 8
#define LSEQ 2304
#define MROWS (BB*LSEQ)   // 18432
#define NCH 64
#define TCH 36            // LSEQ / NCH
#define L2E 1.44269504f

typedef unsigned short u16;
typedef short bf16x8 __attribute__((ext_vector_type(8)));
typedef float f32x4 __attribute__((ext_vector_type(4)));

__device__ __forceinline__ float sigmoid_(float x){ return 1.f/(1.f+__expf(-x)); }
__device__ __forceinline__ float silu_(float x){ return x*sigmoid_(x); }
__device__ __forceinline__ float softplus_(float x){ return (x>20.f)?x:log1pf(__expf(x)); }
__device__ __forceinline__ float gelu_(float x){
  float x3=x*x*x;
  return 0.5f*x*(1.f+tanhf(0.7978845608028654f*(x+0.044715f*x3)));
}
__device__ __forceinline__ float bfu2f(u16 u){
  union{unsigned int i; float f;} c; c.i=((unsigned int)u)<<16; return c.f;
}
__device__ __forceinline__ u16 f2bfu(float f){
  union{float f; unsigned int i;} c; c.f=f;
  unsigned int r = c.i + 0x7FFFu + ((c.i>>16)&1u);
  return (u16)(r>>16);
}
// async global->LDS, 16B per lane; dest must be wave-uniform base + lane*16
__device__ __forceinline__ void gl_lds16(const u16* g, u16* l){
  __builtin_amdgcn_global_load_lds((__attribute__((address_space(1))) void*)g,
      (__attribute__((address_space(3))) void*)l, 16, 0, 0);
}

// ---- weight f32 -> bf16, swizzled to MFMA-fragment-linear layout ----
// Wf[(nt*KT + kt)*512 + l*8 + e] = W[nt*16 + (l&15)][kt*32 + (l>>4)*8 + e]
// so a wave's b-frag (16 n x 32 k) is one coalesced 1KB read.
__device__ __forceinline__ u16 swzw(const float* __restrict__ s, int o, int KT,
                                    int Nsrc, int Ksrc){
  int e = o&7, l = (o>>3)&63, rest = o>>9;
  int kt = rest % KT, nt = rest / KT;
  int n = nt*16 + (l&15);
  int k = kt*32 + ((l>>4)<<3) + e;
  return (n<Nsrc && k<Ksrc) ? f2bfu(s[(size_t)n*Ksrc + k]) : (u16)0;
}

#define O1 589824
#define O2 688128
#define O3 983040
#define O4 1572864
#define O5 2162688
#define O6 2187264
#define OEND 2190336
__global__ void k_cvtall(const float* __restrict__ inw, const float* __restrict__ xpw,
    const float* __restrict__ outw, const float* __restrict__ fc1w,
    const float* __restrict__ fc2w, const float* __restrict__ dtw,
    u16* __restrict__ inw_b, u16* __restrict__ xpw_pad, u16* __restrict__ outw_b,
    u16* __restrict__ fc1w_b, u16* __restrict__ fc2w_b, u16* __restrict__ dtw_pad,
    float* __restrict__ gc){
  int i = blockIdx.x*256+threadIdx.x;
  if(i >= OEND) return;
  if(i < O1){ inw_b[i]   = swzw(inw,  i,    12, 1536, 384); }
  else if(i < O2){ xpw_pad[i-O1] = swzw(xpw,  i-O1, 24, 56,   768); }
  else if(i < O3){ outw_b[i-O2]  = swzw(outw, i-O2, 24, 384,  768); }
  else if(i < O4){ fc1w_b[i-O3]  = swzw(fc1w, i-O3, 12, 1536, 384); }
  else if(i < O5){ fc2w_b[i-O4]  = swzw(fc2w, i-O4, 48, 384,  1536); }
  else if(i < O6){ dtw_pad[i-O5] = swzw(dtw,  i-O5, 1,  768,  24); }
  else { gc[i-O6]=0.f; }
}

// ---------------- transpose (B,C,L) -> (B,L,C) ----------------
__global__ void k_transpose(const float* __restrict__ x, float* __restrict__ xs){
  __shared__ float tile[32][33];
  int b = blockIdx.z;
  int t0 = blockIdx.x*32, c0 = blockIdx.y*32;
  int tx = threadIdx.x, ty = threadIdx.y; // 32 x 8
  const float* xb = x + (size_t)b*DIMC*LSEQ;
  #pragma unroll
  for(int q=0;q<4;q++)
    tile[ty+q*8][tx] = xb[(size_t)(c0+ty+q*8)*LSEQ + t0+tx];
  __syncthreads();
  float* xsb = xs + (size_t)b*LSEQ*DIMC;
  #pragma unroll
  for(int q=0;q<4;q++)
    xsb[(size_t)(t0+ty+q*8)*DIMC + c0+tx] = tile[tx][ty+q*8];
}

// -------- LN stats + LN2 (bf16 out) + attention scores --------
__global__ __launch_bounds__(64) void k_lnstats(const float* __restrict__ xs,
   const float* __restrict__ g1,const float* __restrict__ b1,
   const float* __restrict__ g2,const float* __restrict__ b2,
   const float* __restrict__ apw,const float* __restrict__ apb,
   float* __restrict__ meanr, float* __restrict__ rstdr,
   u16* __restrict__ xn2, float* __restrict__ scores){
  int row = blockIdx.x;
  int lane = threadIdx.x;
  const float* xr = xs + (size_t)row*DIMC;
  float v[6];
  float s=0.f, s2=0.f;
  #pragma unroll
  for(int i=0;i<6;i++){ v[i]=xr[lane+i*64]; s+=v[i]; s2+=v[i]*v[i]; }
  #pragma unroll
  for(int m=32;m>=1;m>>=1){ s += __shfl_xor(s,m); s2 += __shfl_xor(s2,m); }
  float mean = s*(1.f/DIMC);
  float var  = s2*(1.f/DIMC)-mean*mean;
  float rstd = rsqrtf(var+1e-5f);
  if(lane==0){ meanr[row]=mean; rstdr[row]=rstd; }
  float xv1[6];
  #pragma unroll
  for(int i=0;i<6;i++){
    int c = lane+i*64;
    float nx = (v[i]-mean)*rstd;
    xv1[i] = nx*g1[c]+b1[c];
    xn2[(size_t)row*DIMC+c] = f2bfu(nx*g2[c]+b2[c]);
  }
  #pragma unroll
  for(int h=0;h<NHD;h++){
    float p=0.f;
    #pragma unroll
    for(int i=0;i<6;i++) p += xv1[i]*apw[h*DIMC+lane+i*64];
    #pragma unroll
    for(int m=32;m>=1;m>>=1) p += __shfl_xor(p,m);
    if(lane==0) scores[(size_t)row*NHD+h]=p+apb[h];
  }
}

// ---------------- softmax over L per (b,h), in-place ----------------
__global__ __launch_bounds__(256) void k_softmax_L(float* __restrict__ sc){
  int bh = blockIdx.x; int b = bh>>3, h = bh&7;
  int tid = threadIdx.x;
  __shared__ float red[8];
  const size_t base = (size_t)b*LSEQ*NHD + h;
  float mx = -1e30f;
  for(int l=tid;l<LSEQ;l+=256) mx = fmaxf(mx, sc[base + (size_t)l*NHD]);
  #pragma unroll
  for(int m=32;m>=1;m>>=1) mx = fmaxf(mx, __shfl_xor(mx,m));
  if((tid&63)==0) red[tid>>6]=mx;
  __syncthreads();
  mx = fmaxf(fmaxf(red[0],red[1]),fmaxf(red[2],red[3]));
  float sum=0.f;
  for(int l=tid;l<LSEQ;l+=256) sum += __expf(sc[base+(size_t)l*NHD]-mx);
  #pragma unroll
  for(int m=32;m>=1;m>>=1) sum += __shfl_xor(sum,m);
  if((tid&63)==0) red[4+(tid>>6)]=sum;
  __syncthreads();
  float inv = 1.f/(red[4]+red[5]+red[6]+red[7]);
  for(int l=tid;l<LSEQ;l+=256){
    size_t idx = base+(size_t)l*NHD;
    sc[idx] = __expf(sc[idx]-mx)*inv;
  }
}

// gc[b,c] = sum_l mean_h(attn[b,l,h]) * xn1[b,l,c]  (xn1 recomputed, wpool inline)
__global__ __launch_bounds__(384) void k_gc(const float* __restrict__ attn,
    const float* __restrict__ xs, const float* __restrict__ meanr,
    const float* __restrict__ rstdr, const float* __restrict__ g1,
    const float* __restrict__ b1, float* __restrict__ gc){
  int b = blockIdx.x; int chunk = blockIdx.y; int c = threadIdx.x;
  int l0 = chunk*48;
  float acc=0.f, accw=0.f;
  for(int l=0;l<48;l++){
    int row = b*LSEQ + l0+l;
    const float* a = attn + (size_t)row*NHD;
    float ww = (((a[0]+a[1])+(a[2]+a[3]))+((a[4]+a[5])+(a[6]+a[7])))*0.125f;
    acc  += ww*(xs[(size_t)row*DIMC+c]-meanr[row])*rstdr[row];
    accw += ww;
  }
  atomicAdd(&gc[b*DIMC+c], acc*g1[c]+accw*b1[c]);
}

// fused modulation MLP: mod = silu(gc@w1^T+b1)@w2^T+b2   (one block per b)
__global__ __launch_bounds__(256) void k_mod(const float* __restrict__ gc,
    const float* __restrict__ w1, const float* __restrict__ b1,
    const float* __restrict__ w2, const float* __restrict__ b2,
    float* __restrict__ mod){
  __shared__ float hsh[768];
  int b = blockIdx.x, tid = threadIdx.x;
  const float* g = gc + b*DIMC;
  for(int n=tid; n<768; n+=256){
    const float* wr = w1 + (size_t)n*DIMC;
    float acc=0.f;
    for(int k=0;k<DIMC;k++) acc += g[k]*wr[k];
    hsh[n] = silu_(acc+b1[n]);
  }
  __syncthreads();
  for(int n=tid; n<DIMC; n+=256){
    const float* wr = w2 + (size_t)n*768;
    float acc=0.f;
    for(int k=0;k<768;k++) acc += hsh[k]*wr[k];
    mod[b*DIMC+n] = acc+b2[n];
  }
}

// ======  bf16 MFMA GEMM: A via LDS (dbuf, counted vmcnt), B via fragment-
// linear weights straight from L2 into registers (no lB, 16 KB LDS).  ======
// out = epi(A @ W^T + bias).  A:(M,K) bf16 row-major, Wf: fragment-linear.
// Tile 128x128, BK=32, 256 threads = 4 waves (2x2 of 64x64).
template<int EPI>
__global__ __launch_bounds__(256,4) void k_mgemm(
    const u16* __restrict__ A, const u16* __restrict__ Wf,
    const float* __restrict__ bias, void* __restrict__ outp,
    int K, int N, const float* __restrict__ aux, void* __restrict__ outp2)
{
  __shared__ u16 lA[2][4096];   // [buf][kc:4][row:128][8]  (8 KB each)
  int tid = threadIdx.x;
  int m0 = blockIdx.x*128, n0 = blockIdx.y*128;
  int wid = tid>>6, lane = tid&63;
  int wr = wid>>1, wc = wid&1;
  int lrow = lane&15, lk = lane>>4;
  f32x4 acc[4][4];
  #pragma unroll
  for(int i=0;i<4;i++)
    #pragma unroll
    for(int j=0;j<4;j++){ acc[i][j][0]=0.f; acc[i][j][1]=0.f; acc[i][j][2]=0.f; acc[i][j][3]=0.f; }

  int r0 = tid & 127, k0 = tid >> 7;
  const u16* Ag0 = A + (size_t)(m0+r0)*K + k0*8;
  const u16* Ag1 = A + (size_t)(m0+r0)*K + (k0+2)*8;
  const int KT = K >> 5;
  // b-frag base for this wave: nt0 = n0/16 + wc*4; + j*KT*512 per column, + kt*512 per K-step
  const u16* Wfb = Wf + ((size_t)((n0>>4) + wc*4)*KT)*512 + (size_t)lane*8;

  // prologue: stage A tiles 0,1 (2 ops each)
  gl_lds16(Ag0, &lA[0][tid*8]);
  gl_lds16(Ag1, &lA[0][2048+tid*8]);
  if(32 < K){
    gl_lds16(Ag0+32, &lA[1][tid*8]);
    gl_lds16(Ag1+32, &lA[1][2048+tid*8]);
  }

  int cur = 0;
  for(int kb=0; kb<K; kb+=32){
    int kt = kb>>5;
    if(kb+32 < K) asm volatile("s_waitcnt vmcnt(2)" ::: "memory");  // A_cur landed
    else          asm volatile("s_waitcnt vmcnt(0)" ::: "memory");
    __builtin_amdgcn_s_barrier();
    // B fragments straight from L2 (compiler inserts minimal vmcnt before MFMA use)
    bf16x8 bfr[4];
    #pragma unroll
    for(int j=0;j<4;j++)
      bfr[j] = *reinterpret_cast<const bf16x8*>(Wfb + ((size_t)j*KT + kt)*512);
    bf16x8 af[4];
    #pragma unroll
    for(int i=0;i<4;i++)
      af[i] = *reinterpret_cast<const bf16x8*>(&lA[cur][(lk*128 + wr*64 + i*16 + lrow)*8]);
    asm volatile("s_waitcnt lgkmcnt(0)" ::: "memory");  // my LDS reads done
    __builtin_amdgcn_s_barrier();                       // everyone's reads done
    if(kb+64 < K){   // stage A tile kb+64 into just-consumed buffer
      gl_lds16(Ag0 + kb+64, &lA[cur][tid*8]);
      gl_lds16(Ag1 + kb+64, &lA[cur][2048+tid*8]);
    }
    #pragma unroll
    for(int i=0;i<4;i++)
      #pragma unroll
      for(int j=0;j<4;j++)
        acc[i][j] = __builtin_amdgcn_mfma_f32_16x16x32_bf16(af[i], bfr[j], acc[i][j], 0,0,0);
    cur ^= 1;
  }

  #pragma unroll
  for(int i=0;i<4;i++){
    int row = m0 + wr*64 + i*16 + lk*4;
    #pragma unroll
    for(int j=0;j<4;j++){
      int col = n0 + wc*64 + j*16 + lrow;
      float bc = bias ? bias[col] : 0.f;
      f32x4 v = acc[i][j];
      if(EPI==0){
        u16* o = (u16*)outp;
        #pragma unroll
        for(int r=0;r<4;r++) o[(size_t)(row+r)*N + col] = f2bfu(v[r]+bc);
      } else if(EPI==1){
        u16* o = (u16*)outp;
        #pragma unroll
        for(int r=0;r<4;r++) o[(size_t)(row+r)*N + col] = f2bfu(gelu_(v[r]+bc));
      } else if(EPI==2){
        float* o = (float*)outp;
        int bi = row/LSEQ;
        float sc = 1.f + aux[bi*DIMC + col];
        #pragma unroll
        for(int r=0;r<4;r++) o[(size_t)(row+r)*DIMC + col] += (v[r]+bc)*sc;
      } else if(EPI==3){
        float* o = (float*)outp;
        int bi = row/LSEQ, t = row - bi*LSEQ;
        float4 s;
        s.x = aux[(size_t)(row+0)*DIMC+col] + v[0] + bc;
        s.y = aux[(size_t)(row+1)*DIMC+col] + v[1] + bc;
        s.z = aux[(size_t)(row+2)*DIMC+col] + v[2] + bc;
        s.w = aux[(size_t)(row+3)*DIMC+col] + v[3] + bc;
        *reinterpret_cast<float4*>(&o[((size_t)(bi*DIMC+col))*LSEQ + t]) = s;
      } else if(EPI==4){
        float* o = (float*)outp;
        if(col < N){
          #pragma unroll
          for(int r=0;r<4;r++) o[(size_t)(row+r)*N + col] = v[r]+bc;
        }
      } else if(EPI==5){ // split into two (M,768) bf16 outputs
        u16* o = (col < 768) ? (u16*)outp : (u16*)outp2;
        int cc = (col < 768) ? col : col - 768;
        #pragma unroll
        for(int r=0;r<4;r++) o[(size_t)(row+r)*768 + cc] = f2bfu(v[r]+bc);
      } else if(EPI==6){ // dbc f32 (col<56) + dt-input bf16 K-padded to 32
        float* o = (float*)outp;
        u16* o2 = (u16*)outp2;
        #pragma unroll
        for(int r=0;r<4;r++){
          float val = v[r];
          if(col < 56) o[(size_t)(row+r)*56 + col] = val;
          if(col < 32) o2[(size_t)(row+r)*32 + col] = (col<DTRK)? f2bfu(val) : (u16)0;
        }
      } else { // EPI==7: softplus -> bf16
        u16* o = (u16*)outp;
        #pragma unroll
        for(int r=0;r<4;r++) o[(size_t)(row+r)*N + col] = f2bfu(softplus_(v[r]+bc));
      }
    }
  }
}

// ------- causal depthwise conv K=4 + silu, 8 channels/thread (bf16 in/out) -------
__global__ void k_conv(const u16* __restrict__ xm, const float* __restrict__ cw,
                       const float* __restrict__ cb, u16* __restrict__ u){
  int idx = blockIdx.x*256+threadIdx.x;
  if(idx >= MROWS*(DINN/8)) return;
  int j = idx % (DINN/8); int r = idx / (DINN/8);
  int t = r % LSEQ; int d0 = j*8;
  float4 w4_[8];
  #pragma unroll
  for(int e=0;e<8;e++) w4_[e] = reinterpret_cast<const float4*>(cw)[d0+e];
  float acc[8];
  #pragma unroll
  for(int e=0;e<8;e++) acc[e]=cb[d0+e];
  #pragma unroll
  for(int k=0;k<4;k++){
    int tt=t+k-3;
    if(tt>=0){
      uint4 v = *reinterpret_cast<const uint4*>(&xm[(size_t)(r+k-3)*DINN + d0]);
      unsigned vv[4]={v.x,v.y,v.z,v.w};
      #pragma unroll
      for(int e=0;e<8;e++){
        u16 raw = (e&1)? (u16)(vv[e>>1]>>16) : (u16)(vv[e>>1]&0xffffu);
        float wk = (k==0)? w4_[e].x : (k==1)? w4_[e].y : (k==2)? w4_[e].z : w4_[e].w;
        acc[e] += bfu2f(raw)*wk;
      }
    }
  }
  u16 outv[8];
  #pragma unroll
  for(int e=0;e<8;e++) outv[e]=f2bfu(silu_(acc[e]));
  *reinterpret_cast<uint4*>(&u[(size_t)r*DINN+d0]) = *reinterpret_cast<const uint4*>(outv);
}

// ============ chunked selective scan, d-per-thread ============
__global__ __launch_bounds__(256) void k_scan1(
  const u16* __restrict__ dt_, const u16* __restrict__ u_,
  const float* __restrict__ dbc, const float* __restrict__ alog,
  float* __restrict__ ssum, float* __restrict__ hloc)
{
  __shared__ float Bsh[TCH][16];
  int bid = blockIdx.x;
  int b = bid/(NCH*3); int rem = bid%(NCH*3); int ch = rem/3; int dblk = rem%3;
  int tid = threadIdx.x; int d = dblk*256 + tid;
  size_t rbase = (size_t)b*LSEQ + (size_t)ch*TCH;
  for(int j=tid; j<TCH*16; j+=256){
    int row=j>>4, n=j&15;
    Bsh[row][n] = dbc[(rbase+row)*56 + DTRK + n];
  }
  float Acl2[16];
  float a0 = -__expf(alog[(size_t)d*16])*L2E;
  bool fast = true;
  #pragma unroll
  for(int n=0;n<16;n++){
    Acl2[n] = -__expf(alog[(size_t)d*16+n])*L2E;
    float tgt = (float)(n+1)*a0;
    fast = fast && (fabsf(Acl2[n]-tgt) <= 1e-4f*fabsf(tgt));
  }
  float h[16];
  #pragma unroll
  for(int n=0;n<16;n++) h[n]=0.f;
  float S=0.f;
  const u16* dtp = dt_ + rbase*DINN + d;
  const u16* up  = u_  + rbase*DINN + d;
  __syncthreads();
  if(fast){
    for(int t=0;t<TCH;t++){
      float dt = bfu2f(dtp[(size_t)t*DINN]);
      float uv = bfu2f(up[(size_t)t*DINN]);
      float G = dt*uv;
      S += dt;
      float e = exp2f(dt*a0), w = e;
      const float4* b4 = (const float4*)Bsh[t];
      float4 B0=b4[0],B1=b4[1],B2=b4[2],B3=b4[3];
      float Bv[16]={B0.x,B0.y,B0.z,B0.w,B1.x,B1.y,B1.z,B1.w,
                    B2.x,B2.y,B2.z,B2.w,B3.x,B3.y,B3.z,B3.w};
      #pragma unroll
      for(int n=0;n<16;n++){ h[n] = h[n]*w + G*Bv[n]; w *= e; }
    }
  } else {
    for(int t=0;t<TCH;t++){
      float dt = bfu2f(dtp[(size_t)t*DINN]);
      float uv = bfu2f(up[(size_t)t*DINN]);
      float G = dt*uv;
      S += dt;
      const float4* b4 = (const float4*)Bsh[t];
      float4 B0=b4[0],B1=b4[1],B2=b4[2],B3=b4[3];
      float Bv[16]={B0.x,B0.y,B0.z,B0.w,B1.x,B1.y,B1.z,B1.w,
                    B2.x,B2.y,B2.z,B2.w,B3.x,B3.y,B3.z,B3.w};
      #pragma unroll
      for(int n=0;n<16;n++) h[n] = h[n]*exp2f(dt*Acl2[n]) + G*Bv[n];
    }
  }
  ssum[((size_t)b*NCH+ch)*DINN + d] = S;
  float* hp = hloc + (((size_t)b*NCH+ch)*DINN + d)*16;
  #pragma unroll
  for(int n=0;n<16;n++) hp[n] = h[n];
}

__global__ __launch_bounds__(256) void k_scan2(
  const float* __restrict__ ssum, const float* __restrict__ alog,
  float* __restrict__ hl)
{
  int gid = blockIdx.x*256+threadIdx.x;   // B*DINN*16
  int n = gid & 15; int d = (gid>>4)%DINN; int b = gid/(DINN*NSTATE);
  float Acl2 = -__expf(alog[(size_t)d*16+n])*L2E;
  float hin=0.f;
  for(int ch=0; ch<NCH; ch++){
    size_t sidx = ((size_t)b*NCH+ch)*DINN + d;
    size_t idx  = sidx*16 + n;
    float a = exp2f(ssum[sidx]*Acl2);
    float hold = hl[idx];
    hl[idx] = hin;
    hin = a*hin + hold;
  }
}

__global__ __launch_bounds__(256) void k_scan3(
  const u16* __restrict__ dt_, u16* uy, const u16* __restrict__ z_,
  const float* __restrict__ dbc, const float* __restrict__ alog,
  const float* __restrict__ Dp, const float* __restrict__ hin)
{
  __shared__ float BC[TCH][32];
  int bid = blockIdx.x;
  int b = bid/(NCH*3); int rem = bid%(NCH*3); int ch = rem/3; int dblk = rem%3;
  int tid = threadIdx.x; int d = dblk*256 + tid;
  size_t rbase = (size_t)b*LSEQ + (size_t)ch*TCH;
  for(int j=tid; j<TCH*32; j+=256){
    int row=j>>5, c=j&31;
    BC[row][c] = dbc[(rbase+row)*56 + DTRK + c];
  }
  float Acl2[16], h[16];
  const float* hp = hin + (((size_t)b*NCH+ch)*DINN + d)*16;
  float a0 = -__expf(alog[(size_t)d*16])*L2E;
  bool fast = true;
  #pragma unroll
  for(int n=0;n<16;n++){
    Acl2[n] = -__expf(alog[(size_t)d*16+n])*L2E;
    float tgt = (float)(n+1)*a0;
    fast = fast && (fabsf(Acl2[n]-tgt) <= 1e-4f*fabsf(tgt));
    h[n] = hp[n];
  }
  float Dv = Dp[d];
  const u16* dtp = dt_ + rbase*DINN + d;
  u16*       uyp = uy  + rbase*DINN + d;
  const u16* zp  = z_  + rbase*DINN + d;
  __syncthreads();
  if(fast){
    for(int t=0;t<TCH;t++){
      float dt = bfu2f(dtp[(size_t)t*DINN]);
      float uv = bfu2f(uyp[(size_t)t*DINN]);
      float zv = bfu2f(zp[(size_t)t*DINN]);
      float G = dt*uv;
      float e = exp2f(dt*a0), w = e;
      const float4* bc4 = (const float4*)BC[t];
      float4 B0=bc4[0],B1=bc4[1],B2=bc4[2],B3=bc4[3];
      float4 C0=bc4[4],C1=bc4[5],C2=bc4[6],C3=bc4[7];
      float Bv[16]={B0.x,B0.y,B0.z,B0.w,B1.x,B1.y,B1.z,B1.w,
                    B2.x,B2.y,B2.z,B2.w,B3.x,B3.y,B3.z,B3.w};
      float Cv[16]={C0.x,C0.y,C0.z,C0.w,C1.x,C1.y,C1.z,C1.w,
                    C2.x,C2.y,C2.z,C2.w,C3.x,C3.y,C3.z,C3.w};
      float y0=0.f,y1=0.f,y2=0.f,y3=0.f;
      #pragma unroll
      for(int n=0;n<16;n++){
        h[n] = h[n]*w + G*Bv[n];
        w *= e;
        if((n&3)==0) y0 += h[n]*Cv[n];
        else if((n&3)==1) y1 += h[n]*Cv[n];
        else if((n&3)==2) y2 += h[n]*Cv[n];
        else y3 += h[n]*Cv[n];
      }
      float y = (y0+y1)+(y2+y3);
      uyp[(size_t)t*DINN] = f2bfu((y + uv*Dv)*silu_(zv));
    }
  } else {
    for(int t=0;t<TCH;t++){
      float dt = bfu2f(dtp[(size_t)t*DINN]);
      float uv = bfu2f(uyp[(size_t)t*DINN]);
      float zv = bfu2f(zp[(size_t)t*DINN]);
      float G = dt*uv;
      const float4* bc4 = (const float4*)BC[t];
      float4 B0=bc4[0],B1=bc4[1],B2=bc4[2],B3=bc4[3];
      float4 C0=bc4[4],C1=bc4[5],C2=bc4[6],C3=bc4[7];
      float Bv[16]={B0.x,B0.y,B0.z,B0.w,B1.x,B1.y,B1.z,B1.w,
                    B2.x,B2.y,B2.z,B2.w,B3.x,B3.y,B3.z,B3.w};
      float Cv[16]={C0.x,C0.y,C0.z,C0.w,C1.x,C1.y,C1.z,C1.w,
                    C2.x,C2.y,C2.z,C2.w,C3.x,C3.y,C3.z,C3.w};
      float y0=0.f,y1=0.f,y2=0.f,y3=0.f;
      #pragma unroll
      for(int n=0;n<16;n++){
        h[n] = h[n]*exp2f(dt*Acl2[n]) + G*Bv[n];
        if((n&3)==0) y0 += h[n]*Cv[n];
        else if((n&3)==1) y1 += h[n]*Cv[n];
        else if((n&3)==2) y2 += h[n]*Cv[n];
        else y3 += h[n]*Cv[n];
      }
      float y = (y0+y1)+(y2+y3);
      uyp[(size_t)t*DINN] = f2bfu((y + uv*Dv)*silu_(zv));
    }
  }
}

// ---------------- LN3, bf16 out ----------------
__global__ __launch_bounds__(64) void k_ln3(const float* __restrict__ xin,
    const float* __restrict__ g, const float* __restrict__ bb, u16* __restrict__ xout){
  int row = blockIdx.x;
  int lane = threadIdx.x;
  const float* xr = xin + (size_t)row*DIMC;
  float v[6];
  float s=0.f, s2=0.f;
  #pragma unroll
  for(int i=0;i<6;i++){ v[i]=xr[lane+i*64]; s+=v[i]; s2+=v[i]*v[i]; }
  #pragma unroll
  for(int m=32;m>=1;m>>=1){ s += __shfl_xor(s,m); s2 += __shfl_xor(s2,m); }
  float mean = s*(1.f/DIMC);
  float var  = s2*(1.f/DIMC)-mean*mean;
  float rstd = rsqrtf(var+1e-5f);
  #pragma unroll
  for(int i=0;i<6;i++){
    int c = lane+i*64;
    xout[(size_t)row*DIMC+c] = f2bfu((v[i]-mean)*rstd*g[c]+bb[c]);
  }
}

extern "C" void kernel_launch(void* const* d_in, const int* in_sizes, int n_in,
                              void* d_out, int out_size, void* d_ws, size_t ws_size,
                              hipStream_t stream)
{
  const float* x     = (const float*)d_in[0];
  const float* n1g   = (const float*)d_in[1];
  const float* n1b   = (const float*)d_in[2];
  const float* apw   = (const float*)d_in[3];
  const float* apb   = (const float*)d_in[4];
  const float* n2g   = (const float*)d_in[5];
  const float* n2b   = (const float*)d_in[6];
  const float* inw   = (const float*)d_in[7];
  const float* inb   = (const float*)d_in[8];
  const float* convw = (const float*)d_in[9];
  const float* convb = (const float*)d_in[10];
  const float* xpw   = (const float*)d_in[11];
  const float* dtw   = (const float*)d_in[12];
  const float* dtb   = (const float*)d_in[13];
  const float* Alog  = (const float*)d_in[14];
  const float* Dp    = (const float*)d_in[15];
  const float* outw  = (const float*)d_in[16];
  const float* outb  = (const float*)d_in[17];
  const float* modw1 = (const float*)d_in[18];
  const float* modb1 = (const float*)d_in[19];
  const float* modw2 = (const float*)d_in[20];
  const float* modb2 = (const float*)d_in[21];
  const float* n3g   = (const float*)d_in[22];
  const float* n3b   = (const float*)d_in[23];
  const float* fc1w  = (const float*)d_in[24];
  const float* fc1b  = (const float*)d_in[25];
  const float* fc2w  = (const float*)d_in[26];
  const float* fc2b  = (const float*)d_in[27];

  // ---- workspace layout (f32 slots), total ~30.95M f = 123.8 MB ----
  float* ws = (float*)d_ws;
  float* XS    = ws;                       // 7,077,888 f
  float* R1    = ws + 7077888;             // 14,155,776 f multi-use region
  u16*   XMb   = (u16*)R1;
  u16*   DTb   = (u16*)R1;
  float* SSUM  = R1 + 7077888;             // 393,216 f
  float* HL    = R1 + 7471104;             // 6,291,456 f
  u16*   F1b   = (u16*)R1;
  u16*   Zb    = (u16*)(ws + 21233664);    // 14,155,776 u16 (= 7,077,888 f)
  float* DBC   = ws + 28311552;            // 1,032,192 f
  float* WB    = ws + 29343744;            // bf16 weights, 1,081,344 f slots
  u16*   inw_b   = (u16*)WB;                     // 589,824 sh (frag-linear)
  u16*   xpw_pad = inw_b + 589824;               // 98,304 sh
  u16*   outw_b  = xpw_pad + 98304;              // 294,912 sh
  u16*   fc1w_b  = outw_b + 294912;              // 589,824 sh
  u16*   fc2w_b  = fc1w_b + 589824;              // 589,824 sh
  float* SCORES= ws + 30425088;            // 147,456 f
  float* MEANR = ws + 30590976;            // 18,432
  float* RSTDR = ws + 30609408;            // 18,432
  float* GC    = ws + 30627840;            // 3,072
  float* MOD   = ws + 30637056;            // 3,072
  u16*   DT32b = (u16*)(ws + 30640128);    // 589,824 sh (M x 32 dt-input, K-pad)
  u16*   dtw_pad=(u16*)(ws + 30935040);    // 24,576 sh (frag-linear 768x32)
  (void)ws_size; (void)n_in; (void)in_sizes; (void)out_size;

  // d_out as scratch: XN2b bf16 -> Ub bf16 -> Y bf16 (in-place over Ub) -> Hb bf16
  u16* XN2b = (u16*)d_out;
  u16* Ub   = (u16*)d_out;
  u16* Hb   = (u16*)d_out;

  // fused weight conversion (frag-linear swizzle) + GC zero
  k_cvtall<<<(OEND+255)/256, 256, 0, stream>>>(inw, xpw, outw, fc1w, fc2w, dtw,
      inw_b, xpw_pad, outw_b, fc1w_b, fc2w_b, dtw_pad, GC);

  k_transpose<<<dim3(72,12,8), dim3(32,8), 0, stream>>>(x, XS);
  k_lnstats<<<MROWS, 64, 0, stream>>>(XS, n1g,n1b,n2g,n2b, apw,apb, MEANR, RSTDR, XN2b, SCORES);
  k_softmax_L<<<BB*NHD, 256, 0, stream>>>(SCORES);
  k_gc<<<dim3(BB,48), 384, 0, stream>>>(SCORES, XS, MEANR, RSTDR, n1g, n1b, GC);
  k_mod<<<BB, 256, 0, stream>>>(GC, modw1, modb1, modw2, modb2, MOD);

  // in_proj fused: [XMb | Zb] = XN2 @ inw^T + inb   (K=384, N=1536, split store)
  k_mgemm<5><<<dim3(144,12), 256, 0, stream>>>(XN2b, inw_b, inb, XMb, 384, 1536, nullptr, Zb);
  // conv + silu -> Ub (bf16, in d_out; XN2b dead)
  k_conv<<<(MROWS*(DINN/8)+255)/256, 256, 0, stream>>>(XMb, convw, convb, Ub);
  // dbc = u @ xp_w^T (K=768): f32 DBC (col<56) + bf16 K-padded dt-input DT32b
  k_mgemm<6><<<dim3(144,1), 256, 0, stream>>>(Ub, xpw_pad, nullptr, DBC, 768, 56, nullptr, DT32b);
  // delta = softplus(DT32 @ dtw_pad^T + dtb) -> DTb bf16 (over dead XMb), K=32 MFMA
  k_mgemm<7><<<dim3(144,6), 256, 0, stream>>>(DT32b, dtw_pad, dtb, DTb, 32, 768, nullptr, nullptr);
  // chunked scan (d-per-thread, A-structure fast path)
  k_scan1<<<BB*NCH*3, 256, 0, stream>>>(DTb, Ub, DBC, Alog, SSUM, HL);
  k_scan2<<<384, 256, 0, stream>>>(SSUM, Alog, HL);
  k_scan3<<<BB*NCH*3, 256, 0, stream>>>(DTb, Ub, Zb, DBC, Alog, Dp, HL);
  // XS += (y @ out_w^T + out_b) * (1 + mod)   (K=768, N=384); Y lives in Ub slot
  k_mgemm<2><<<dim3(144,3), 256, 0, stream>>>(Ub, outw_b, outb, XS, 768, 384, MOD, nullptr);
  // Hb = LN3(XS)  (bf16, into d_out; Y dead)
  k_ln3<<<MROWS, 64, 0, stream>>>(XS, n3g, n3b, Hb);
  // F1b = gelu(H @ fc1_w^T + fc1_b)   (K=384, N=1536; overlays R1)
  k_mgemm<1><<<dim3(144,12), 256, 0, stream>>>(Hb, fc1w_b, fc1b, F1b, 384, 1536, nullptr, nullptr);
  // d_out = transpose(XS + F1 @ fc2_w^T + fc2_b)   (K=1536, N=384)
  k_mgemm<3><<<dim3(144,3), 256, 0, stream>>>(F1b, fc2w_b, fc2b, d_out, 1536, 384, XS, nullptr);
}

// Round 9
// 498.577 us; speedup vs baseline: 1.1140x; 1.1140x over previous
//
#include <hip/hip_runtime.h>
#include <math.h>

#define DIMC 384
#define NHD 8
#define NSTATE 16
#define DINN 768
#define DTRK 24
#define BB 8
#define LSEQ 2304
#define MROWS (BB*LSEQ)   // 18432
#define NCH 64
#define TCH 36            // LSEQ / NCH
#define L2E 1.44269504f

typedef unsigned short u16;
typedef short bf16x8 __attribute__((ext_vector_type(8)));
typedef float f32x4 __attribute__((ext_vector_type(4)));

__device__ __forceinline__ float sigmoid_(float x){ return 1.f/(1.f+__expf(-x)); }
__device__ __forceinline__ float silu_(float x){ return x*sigmoid_(x); }
__device__ __forceinline__ float softplus_(float x){ return (x>20.f)?x:log1pf(__expf(x)); }
__device__ __forceinline__ float gelu_(float x){
  float x3=x*x*x;
  return 0.5f*x*(1.f+tanhf(0.7978845608028654f*(x+0.044715f*x3)));
}
__device__ __forceinline__ float bfu2f(u16 u){
  union{unsigned int i; float f;} c; c.i=((unsigned int)u)<<16; return c.f;
}
__device__ __forceinline__ u16 f2bfu(float f){
  union{float f; unsigned int i;} c; c.f=f;
  unsigned int r = c.i + 0x7FFFu + ((c.i>>16)&1u);
  return (u16)(r>>16);
}
// async global->LDS, 16B per lane; dest must be wave-uniform base + lane*16
__device__ __forceinline__ void gl_lds16(const u16* g, u16* l){
  __builtin_amdgcn_global_load_lds((__attribute__((address_space(1))) void*)g,
      (__attribute__((address_space(3))) void*)l, 16, 0, 0);
}

// ---- weight f32 -> bf16, swizzled to MFMA-fragment-linear layout ----
// Wf[(nt*KT + kt)*512 + l*8 + e] = W[nt*16 + (l&15)][kt*32 + (l>>4)*8 + e]
__device__ __forceinline__ u16 swzw(const float* __restrict__ s, int o, int KT,
                                    int Nsrc, int Ksrc){
  int e = o&7, l = (o>>3)&63, rest = o>>9;
  int kt = rest % KT, nt = rest / KT;
  int n = nt*16 + (l&15);
  int k = kt*32 + ((l>>4)<<3) + e;
  return (n<Nsrc && k<Ksrc) ? f2bfu(s[(size_t)n*Ksrc + k]) : (u16)0;
}

#define O1 589824
#define O2 688128
#define O3 983040
#define O4 1572864
#define O5 2162688
#define O6 2187264
#define OEND 2190336
__global__ void k_cvtall(const float* __restrict__ inw, const float* __restrict__ xpw,
    const float* __restrict__ outw, const float* __restrict__ fc1w,
    const float* __restrict__ fc2w, const float* __restrict__ dtw,
    u16* __restrict__ inw_b, u16* __restrict__ xpw_pad, u16* __restrict__ outw_b,
    u16* __restrict__ fc1w_b, u16* __restrict__ fc2w_b, u16* __restrict__ dtw_pad,
    float* __restrict__ gc){
  int i = blockIdx.x*256+threadIdx.x;
  if(i >= OEND) return;
  if(i < O1){ inw_b[i]   = swzw(inw,  i,    12, 1536, 384); }
  else if(i < O2){ xpw_pad[i-O1] = swzw(xpw,  i-O1, 24, 56,   768); }
  else if(i < O3){ outw_b[i-O2]  = swzw(outw, i-O2, 24, 384,  768); }
  else if(i < O4){ fc1w_b[i-O3]  = swzw(fc1w, i-O3, 12, 1536, 384); }
  else if(i < O5){ fc2w_b[i-O4]  = swzw(fc2w, i-O4, 48, 384,  1536); }
  else if(i < O6){ dtw_pad[i-O5] = swzw(dtw,  i-O5, 1,  768,  24); }
  else { gc[i-O6]=0.f; }
}

// ---------------- transpose (B,C,L) -> (B,L,C) ----------------
__global__ void k_transpose(const float* __restrict__ x, float* __restrict__ xs){
  __shared__ float tile[32][33];
  int b = blockIdx.z;
  int t0 = blockIdx.x*32, c0 = blockIdx.y*32;
  int tx = threadIdx.x, ty = threadIdx.y; // 32 x 8
  const float* xb = x + (size_t)b*DIMC*LSEQ;
  #pragma unroll
  for(int q=0;q<4;q++)
    tile[ty+q*8][tx] = xb[(size_t)(c0+ty+q*8)*LSEQ + t0+tx];
  __syncthreads();
  float* xsb = xs + (size_t)b*LSEQ*DIMC;
  #pragma unroll
  for(int q=0;q<4;q++)
    xsb[(size_t)(t0+ty+q*8)*DIMC + c0+tx] = tile[tx][ty+q*8];
}

// -------- LN stats + LN2 (bf16 out) + attention scores --------
__global__ __launch_bounds__(64) void k_lnstats(const float* __restrict__ xs,
   const float* __restrict__ g1,const float* __restrict__ b1,
   const float* __restrict__ g2,const float* __restrict__ b2,
   const float* __restrict__ apw,const float* __restrict__ apb,
   float* __restrict__ meanr, float* __restrict__ rstdr,
   u16* __restrict__ xn2, float* __restrict__ scores){
  int row = blockIdx.x;
  int lane = threadIdx.x;
  const float* xr = xs + (size_t)row*DIMC;
  float v[6];
  float s=0.f, s2=0.f;
  #pragma unroll
  for(int i=0;i<6;i++){ v[i]=xr[lane+i*64]; s+=v[i]; s2+=v[i]*v[i]; }
  #pragma unroll
  for(int m=32;m>=1;m>>=1){ s += __shfl_xor(s,m); s2 += __shfl_xor(s2,m); }
  float mean = s*(1.f/DIMC);
  float var  = s2*(1.f/DIMC)-mean*mean;
  float rstd = rsqrtf(var+1e-5f);
  if(lane==0){ meanr[row]=mean; rstdr[row]=rstd; }
  float xv1[6];
  #pragma unroll
  for(int i=0;i<6;i++){
    int c = lane+i*64;
    float nx = (v[i]-mean)*rstd;
    xv1[i] = nx*g1[c]+b1[c];
    xn2[(size_t)row*DIMC+c] = f2bfu(nx*g2[c]+b2[c]);
  }
  #pragma unroll
  for(int h=0;h<NHD;h++){
    float p=0.f;
    #pragma unroll
    for(int i=0;i<6;i++) p += xv1[i]*apw[h*DIMC+lane+i*64];
    #pragma unroll
    for(int m=32;m>=1;m>>=1) p += __shfl_xor(p,m);
    if(lane==0) scores[(size_t)row*NHD+h]=p+apb[h];
  }
}

// ---------------- softmax over L per (b,h), in-place ----------------
__global__ __launch_bounds__(256) void k_softmax_L(float* __restrict__ sc){
  int bh = blockIdx.x; int b = bh>>3, h = bh&7;
  int tid = threadIdx.x;
  __shared__ float red[8];
  const size_t base = (size_t)b*LSEQ*NHD + h;
  float mx = -1e30f;
  for(int l=tid;l<LSEQ;l+=256) mx = fmaxf(mx, sc[base + (size_t)l*NHD]);
  #pragma unroll
  for(int m=32;m>=1;m>>=1) mx = fmaxf(mx, __shfl_xor(mx,m));
  if((tid&63)==0) red[tid>>6]=mx;
  __syncthreads();
  mx = fmaxf(fmaxf(red[0],red[1]),fmaxf(red[2],red[3]));
  float sum=0.f;
  for(int l=tid;l<LSEQ;l+=256) sum += __expf(sc[base+(size_t)l*NHD]-mx);
  #pragma unroll
  for(int m=32;m>=1;m>>=1) sum += __shfl_xor(sum,m);
  if((tid&63)==0) red[4+(tid>>6)]=sum;
  __syncthreads();
  float inv = 1.f/(red[4]+red[5]+red[6]+red[7]);
  for(int l=tid;l<LSEQ;l+=256){
    size_t idx = base+(size_t)l*NHD;
    sc[idx] = __expf(sc[idx]-mx)*inv;
  }
}

// gc[b,c] = sum_l mean_h(attn[b,l,h]) * xn1[b,l,c]  (xn1 recomputed, wpool inline)
__global__ __launch_bounds__(384) void k_gc(const float* __restrict__ attn,
    const float* __restrict__ xs, const float* __restrict__ meanr,
    const float* __restrict__ rstdr, const float* __restrict__ g1,
    const float* __restrict__ b1, float* __restrict__ gc){
  int b = blockIdx.x; int chunk = blockIdx.y; int c = threadIdx.x;
  int l0 = chunk*48;
  float acc=0.f, accw=0.f;
  for(int l=0;l<48;l++){
    int row = b*LSEQ + l0+l;
    const float* a = attn + (size_t)row*NHD;
    float ww = (((a[0]+a[1])+(a[2]+a[3]))+((a[4]+a[5])+(a[6]+a[7])))*0.125f;
    acc  += ww*(xs[(size_t)row*DIMC+c]-meanr[row])*rstdr[row];
    accw += ww;
  }
  atomicAdd(&gc[b*DIMC+c], acc*g1[c]+accw*b1[c]);
}

// mod MLP stage 1: MODH[b,n] = silu(gc[b,:]@w1[n,:]+b1[n]); 4 threads/output
__global__ __launch_bounds__(256) void k_mod1(const float* __restrict__ gc,
    const float* __restrict__ w1, const float* __restrict__ b1,
    float* __restrict__ modh){
  int b = blockIdx.x; int n = blockIdx.y*64 + (threadIdx.x>>2);
  int sub = threadIdx.x&3;
  const float4* g = (const float4*)(gc + b*DIMC) + sub*24;
  const float4* wr = (const float4*)(w1 + (size_t)n*DIMC) + sub*24;
  float acc=0.f;
  #pragma unroll
  for(int k=0;k<24;k++){
    float4 a=g[k], w=wr[k];
    acc += a.x*w.x + a.y*w.y + a.z*w.z + a.w*w.w;
  }
  acc += __shfl_xor(acc,1); acc += __shfl_xor(acc,2);
  if(sub==0) modh[b*768+n] = silu_(acc+b1[n]);
}
// mod MLP stage 2: MOD[b,n] = modh[b,:]@w2[n,:]+b2[n]; 4 threads/output
__global__ __launch_bounds__(256) void k_mod2(const float* __restrict__ modh,
    const float* __restrict__ w2, const float* __restrict__ b2,
    float* __restrict__ mod){
  int b = blockIdx.x; int n = blockIdx.y*64 + (threadIdx.x>>2);
  int sub = threadIdx.x&3;
  const float4* g = (const float4*)(modh + b*768) + sub*48;
  const float4* wr = (const float4*)(w2 + (size_t)n*768) + sub*48;
  float acc=0.f;
  #pragma unroll
  for(int k=0;k<48;k++){
    float4 a=g[k], w=wr[k];
    acc += a.x*w.x + a.y*w.y + a.z*w.z + a.w*w.w;
  }
  acc += __shfl_xor(acc,1); acc += __shfl_xor(acc,2);
  if(sub==0) mod[b*DIMC+n] = acc+b2[n];
}

// ======  bf16 MFMA GEMM: A via LDS (dbuf, counted vmcnt), B via fragment-
// linear weights straight from L2 into registers (no lB, 16 KB LDS).  ======
template<int EPI>
__global__ __launch_bounds__(256,4) void k_mgemm(
    const u16* __restrict__ A, const u16* __restrict__ Wf,
    const float* __restrict__ bias, void* __restrict__ outp,
    int K, int N, const float* __restrict__ aux, void* __restrict__ outp2)
{
  __shared__ u16 lA[2][4096];   // [buf][kc:4][row:128][8]  (8 KB each)
  int tid = threadIdx.x;
  int m0 = blockIdx.x*128, n0 = blockIdx.y*128;
  int wid = tid>>6, lane = tid&63;
  int wr = wid>>1, wc = wid&1;
  int lrow = lane&15, lk = lane>>4;
  f32x4 acc[4][4];
  #pragma unroll
  for(int i=0;i<4;i++)
    #pragma unroll
    for(int j=0;j<4;j++){ acc[i][j][0]=0.f; acc[i][j][1]=0.f; acc[i][j][2]=0.f; acc[i][j][3]=0.f; }

  int r0 = tid & 127, k0 = tid >> 7;
  const u16* Ag0 = A + (size_t)(m0+r0)*K + k0*8;
  const u16* Ag1 = A + (size_t)(m0+r0)*K + (k0+2)*8;
  const int KT = K >> 5;
  const u16* Wfb = Wf + ((size_t)((n0>>4) + wc*4)*KT)*512 + (size_t)lane*8;

  gl_lds16(Ag0, &lA[0][tid*8]);
  gl_lds16(Ag1, &lA[0][2048+tid*8]);
  if(32 < K){
    gl_lds16(Ag0+32, &lA[1][tid*8]);
    gl_lds16(Ag1+32, &lA[1][2048+tid*8]);
  }

  int cur = 0;
  for(int kb=0; kb<K; kb+=32){
    int kt = kb>>5;
    if(kb+32 < K) asm volatile("s_waitcnt vmcnt(2)" ::: "memory");
    else          asm volatile("s_waitcnt vmcnt(0)" ::: "memory");
    __builtin_amdgcn_s_barrier();
    bf16x8 bfr[4];
    #pragma unroll
    for(int j=0;j<4;j++)
      bfr[j] = *reinterpret_cast<const bf16x8*>(Wfb + ((size_t)j*KT + kt)*512);
    bf16x8 af[4];
    #pragma unroll
    for(int i=0;i<4;i++)
      af[i] = *reinterpret_cast<const bf16x8*>(&lA[cur][(lk*128 + wr*64 + i*16 + lrow)*8]);
    asm volatile("s_waitcnt lgkmcnt(0)" ::: "memory");
    __builtin_amdgcn_s_barrier();
    if(kb+64 < K){
      gl_lds16(Ag0 + kb+64, &lA[cur][tid*8]);
      gl_lds16(Ag1 + kb+64, &lA[cur][2048+tid*8]);
    }
    #pragma unroll
    for(int i=0;i<4;i++)
      #pragma unroll
      for(int j=0;j<4;j++)
        acc[i][j] = __builtin_amdgcn_mfma_f32_16x16x32_bf16(af[i], bfr[j], acc[i][j], 0,0,0);
    cur ^= 1;
  }

  #pragma unroll
  for(int i=0;i<4;i++){
    int row = m0 + wr*64 + i*16 + lk*4;
    #pragma unroll
    for(int j=0;j<4;j++){
      int col = n0 + wc*64 + j*16 + lrow;
      float bc = bias ? bias[col] : 0.f;
      f32x4 v = acc[i][j];
      if(EPI==0){
        u16* o = (u16*)outp;
        #pragma unroll
        for(int r=0;r<4;r++) o[(size_t)(row+r)*N + col] = f2bfu(v[r]+bc);
      } else if(EPI==1){
        u16* o = (u16*)outp;
        #pragma unroll
        for(int r=0;r<4;r++) o[(size_t)(row+r)*N + col] = f2bfu(gelu_(v[r]+bc));
      } else if(EPI==2){
        float* o = (float*)outp;
        int bi = row/LSEQ;
        float sc = 1.f + aux[bi*DIMC + col];
        #pragma unroll
        for(int r=0;r<4;r++) o[(size_t)(row+r)*DIMC + col] += (v[r]+bc)*sc;
      } else if(EPI==3){
        float* o = (float*)outp;
        int bi = row/LSEQ, t = row - bi*LSEQ;
        float4 s;
        s.x = aux[(size_t)(row+0)*DIMC+col] + v[0] + bc;
        s.y = aux[(size_t)(row+1)*DIMC+col] + v[1] + bc;
        s.z = aux[(size_t)(row+2)*DIMC+col] + v[2] + bc;
        s.w = aux[(size_t)(row+3)*DIMC+col] + v[3] + bc;
        *reinterpret_cast<float4*>(&o[((size_t)(bi*DIMC+col))*LSEQ + t]) = s;
      } else if(EPI==4){
        float* o = (float*)outp;
        if(col < N){
          #pragma unroll
          for(int r=0;r<4;r++) o[(size_t)(row+r)*N + col] = v[r]+bc;
        }
      } else if(EPI==5){ // split into two (M,768) bf16 outputs
        u16* o = (col < 768) ? (u16*)outp : (u16*)outp2;
        int cc = (col < 768) ? col : col - 768;
        #pragma unroll
        for(int r=0;r<4;r++) o[(size_t)(row+r)*768 + cc] = f2bfu(v[r]+bc);
      } else if(EPI==6){ // dbc f32 (col<56) + dt-input bf16 K-padded to 32
        float* o = (float*)outp;
        u16* o2 = (u16*)outp2;
        #pragma unroll
        for(int r=0;r<4;r++){
          float val = v[r];
          if(col < 56) o[(size_t)(row+r)*56 + col] = val;
          if(col < 32) o2[(size_t)(row+r)*32 + col] = (col<DTRK)? f2bfu(val) : (u16)0;
        }
      } else { // EPI==7: softplus -> bf16
        u16* o = (u16*)outp;
        #pragma unroll
        for(int r=0;r<4;r++) o[(size_t)(row+r)*N + col] = f2bfu(softplus_(v[r]+bc));
      }
    }
  }
}

// ------- causal depthwise conv K=4 + silu, 8 channels/thread (bf16 in/out) -------
__global__ void k_conv(const u16* __restrict__ xm, const float* __restrict__ cw,
                       const float* __restrict__ cb, u16* __restrict__ u){
  int idx = blockIdx.x*256+threadIdx.x;
  if(idx >= MROWS*(DINN/8)) return;
  int j = idx % (DINN/8); int r = idx / (DINN/8);
  int t = r % LSEQ; int d0 = j*8;
  float4 w4_[8];
  #pragma unroll
  for(int e=0;e<8;e++) w4_[e] = reinterpret_cast<const float4*>(cw)[d0+e];
  float acc[8];
  #pragma unroll
  for(int e=0;e<8;e++) acc[e]=cb[d0+e];
  #pragma unroll
  for(int k=0;k<4;k++){
    int tt=t+k-3;
    if(tt>=0){
      uint4 v = *reinterpret_cast<const uint4*>(&xm[(size_t)(r+k-3)*DINN + d0]);
      unsigned vv[4]={v.x,v.y,v.z,v.w};
      #pragma unroll
      for(int e=0;e<8;e++){
        u16 raw = (e&1)? (u16)(vv[e>>1]>>16) : (u16)(vv[e>>1]&0xffffu);
        float wk = (k==0)? w4_[e].x : (k==1)? w4_[e].y : (k==2)? w4_[e].z : w4_[e].w;
        acc[e] += bfu2f(raw)*wk;
      }
    }
  }
  u16 outv[8];
  #pragma unroll
  for(int e=0;e<8;e++) outv[e]=f2bfu(silu_(acc[e]));
  *reinterpret_cast<uint4*>(&u[(size_t)r*DINN+d0]) = *reinterpret_cast<const uint4*>(outv);
}

// ============ chunked selective scan, d-per-thread ============
__global__ __launch_bounds__(256) void k_scan1(
  const u16* __restrict__ dt_, const u16* __restrict__ u_,
  const float* __restrict__ dbc, const float* __restrict__ alog,
  float* __restrict__ ssum, float* __restrict__ hloc)
{
  __shared__ float Bsh[TCH][16];
  int bid = blockIdx.x;
  int b = bid/(NCH*3); int rem = bid%(NCH*3); int ch = rem/3; int dblk = rem%3;
  int tid = threadIdx.x; int d = dblk*256 + tid;
  size_t rbase = (size_t)b*LSEQ + (size_t)ch*TCH;
  for(int j=tid; j<TCH*16; j+=256){
    int row=j>>4, n=j&15;
    Bsh[row][n] = dbc[(rbase+row)*56 + DTRK + n];
  }
  float Acl2[16];
  float a0 = -__expf(alog[(size_t)d*16])*L2E;
  bool fast = true;
  #pragma unroll
  for(int n=0;n<16;n++){
    Acl2[n] = -__expf(alog[(size_t)d*16+n])*L2E;
    float tgt = (float)(n+1)*a0;
    fast = fast && (fabsf(Acl2[n]-tgt) <= 1e-4f*fabsf(tgt));
  }
  float h[16];
  #pragma unroll
  for(int n=0;n<16;n++) h[n]=0.f;
  float S=0.f;
  const u16* dtp = dt_ + rbase*DINN + d;
  const u16* up  = u_  + rbase*DINN + d;
  __syncthreads();
  if(fast){
    for(int t=0;t<TCH;t++){
      float dt = bfu2f(dtp[(size_t)t*DINN]);
      float uv = bfu2f(up[(size_t)t*DINN]);
      float G = dt*uv;
      S += dt;
      float e = exp2f(dt*a0), w = e;
      const float4* b4 = (const float4*)Bsh[t];
      float4 B0=b4[0],B1=b4[1],B2=b4[2],B3=b4[3];
      float Bv[16]={B0.x,B0.y,B0.z,B0.w,B1.x,B1.y,B1.z,B1.w,
                    B2.x,B2.y,B2.z,B2.w,B3.x,B3.y,B3.z,B3.w};
      #pragma unroll
      for(int n=0;n<16;n++){ h[n] = h[n]*w + G*Bv[n]; w *= e; }
    }
  } else {
    for(int t=0;t<TCH;t++){
      float dt = bfu2f(dtp[(size_t)t*DINN]);
      float uv = bfu2f(up[(size_t)t*DINN]);
      float G = dt*uv;
      S += dt;
      const float4* b4 = (const float4*)Bsh[t];
      float4 B0=b4[0],B1=b4[1],B2=b4[2],B3=b4[3];
      float Bv[16]={B0.x,B0.y,B0.z,B0.w,B1.x,B1.y,B1.z,B1.w,
                    B2.x,B2.y,B2.z,B2.w,B3.x,B3.y,B3.z,B3.w};
      #pragma unroll
      for(int n=0;n<16;n++) h[n] = h[n]*exp2f(dt*Acl2[n]) + G*Bv[n];
    }
  }
  ssum[((size_t)b*NCH+ch)*DINN + d] = S;
  float* hp = hloc + (((size_t)b*NCH+ch)*DINN + d)*16;
  #pragma unroll
  for(int n=0;n<16;n++) hp[n] = h[n];
}

__global__ __launch_bounds__(256) void k_scan2(
  const float* __restrict__ ssum, const float* __restrict__ alog,
  float* __restrict__ hl)
{
  int gid = blockIdx.x*256+threadIdx.x;   // B*DINN*16
  int n = gid & 15; int d = (gid>>4)%DINN; int b = gid/(DINN*NSTATE);
  float Acl2 = -__expf(alog[(size_t)d*16+n])*L2E;
  float hin=0.f;
  for(int ch=0; ch<NCH; ch++){
    size_t sidx = ((size_t)b*NCH+ch)*DINN + d;
    size_t idx  = sidx*16 + n;
    float a = exp2f(ssum[sidx]*Acl2);
    float hold = hl[idx];
    hl[idx] = hin;
    hin = a*hin + hold;
  }
}

__global__ __launch_bounds__(256) void k_scan3(
  const u16* __restrict__ dt_, u16* uy, const u16* __restrict__ z_,
  const float* __restrict__ dbc, const float* __restrict__ alog,
  const float* __restrict__ Dp, const float* __restrict__ hin)
{
  __shared__ float BC[TCH][32];
  int bid = blockIdx.x;
  int b = bid/(NCH*3); int rem = bid%(NCH*3); int ch = rem/3; int dblk = rem%3;
  int tid = threadIdx.x; int d = dblk*256 + tid;
  size_t rbase = (size_t)b*LSEQ + (size_t)ch*TCH;
  for(int j=tid; j<TCH*32; j+=256){
    int row=j>>5, c=j&31;
    BC[row][c] = dbc[(rbase+row)*56 + DTRK + c];
  }
  float Acl2[16], h[16];
  const float* hp = hin + (((size_t)b*NCH+ch)*DINN + d)*16;
  float a0 = -__expf(alog[(size_t)d*16])*L2E;
  bool fast = true;
  #pragma unroll
  for(int n=0;n<16;n++){
    Acl2[n] = -__expf(alog[(size_t)d*16+n])*L2E;
    float tgt = (float)(n+1)*a0;
    fast = fast && (fabsf(Acl2[n]-tgt) <= 1e-4f*fabsf(tgt));
    h[n] = hp[n];
  }
  float Dv = Dp[d];
  const u16* dtp = dt_ + rbase*DINN + d;
  u16*       uyp = uy  + rbase*DINN + d;
  const u16* zp  = z_  + rbase*DINN + d;
  __syncthreads();
  if(fast){
    for(int t=0;t<TCH;t++){
      float dt = bfu2f(dtp[(size_t)t*DINN]);
      float uv = bfu2f(uyp[(size_t)t*DINN]);
      float zv = bfu2f(zp[(size_t)t*DINN]);
      float G = dt*uv;
      float e = exp2f(dt*a0), w = e;
      const float4* bc4 = (const float4*)BC[t];
      float4 B0=bc4[0],B1=bc4[1],B2=bc4[2],B3=bc4[3];
      float4 C0=bc4[4],C1=bc4[5],C2=bc4[6],C3=bc4[7];
      float Bv[16]={B0.x,B0.y,B0.z,B0.w,B1.x,B1.y,B1.z,B1.w,
                    B2.x,B2.y,B2.z,B2.w,B3.x,B3.y,B3.z,B3.w};
      float Cv[16]={C0.x,C0.y,C0.z,C0.w,C1.x,C1.y,C1.z,C1.w,
                    C2.x,C2.y,C2.z,C2.w,C3.x,C3.y,C3.z,C3.w};
      float y0=0.f,y1=0.f,y2=0.f,y3=0.f;
      #pragma unroll
      for(int n=0;n<16;n++){
        h[n] = h[n]*w + G*Bv[n];
        w *= e;
        if((n&3)==0) y0 += h[n]*Cv[n];
        else if((n&3)==1) y1 += h[n]*Cv[n];
        else if((n&3)==2) y2 += h[n]*Cv[n];
        else y3 += h[n]*Cv[n];
      }
      float y = (y0+y1)+(y2+y3);
      uyp[(size_t)t*DINN] = f2bfu((y + uv*Dv)*silu_(zv));
    }
  } else {
    for(int t=0;t<TCH;t++){
      float dt = bfu2f(dtp[(size_t)t*DINN]);
      float uv = bfu2f(uyp[(size_t)t*DINN]);
      float zv = bfu2f(zp[(size_t)t*DINN]);
      float G = dt*uv;
      const float4* bc4 = (const float4*)BC[t];
      float4 B0=bc4[0],B1=bc4[1],B2=bc4[2],B3=bc4[3];
      float4 C0=bc4[4],C1=bc4[5],C2=bc4[6],C3=bc4[7];
      float Bv[16]={B0.x,B0.y,B0.z,B0.w,B1.x,B1.y,B1.z,B1.w,
                    B2.x,B2.y,B2.z,B2.w,B3.x,B3.y,B3.z,B3.w};
      float Cv[16]={C0.x,C0.y,C0.z,C0.w,C1.x,C1.y,C1.z,C1.w,
                    C2.x,C2.y,C2.z,C2.w,C3.x,C3.y,C3.z,C3.w};
      float y0=0.f,y1=0.f,y2=0.f,y3=0.f;
      #pragma unroll
      for(int n=0;n<16;n++){
        h[n] = h[n]*exp2f(dt*Acl2[n]) + G*Bv[n];
        if((n&3)==0) y0 += h[n]*Cv[n];
        else if((n&3)==1) y1 += h[n]*Cv[n];
        else if((n&3)==2) y2 += h[n]*Cv[n];
        else y3 += h[n]*Cv[n];
      }
      float y = (y0+y1)+(y2+y3);
      uyp[(size_t)t*DINN] = f2bfu((y + uv*Dv)*silu_(zv));
    }
  }
}

// ---------------- LN3, bf16 out ----------------
__global__ __launch_bounds__(64) void k_ln3(const float* __restrict__ xin,
    const float* __restrict__ g, const float* __restrict__ bb, u16* __restrict__ xout){
  int row = blockIdx.x;
  int lane = threadIdx.x;
  const float* xr = xin + (size_t)row*DIMC;
  float v[6];
  float s=0.f, s2=0.f;
  #pragma unroll
  for(int i=0;i<6;i++){ v[i]=xr[lane+i*64]; s+=v[i]; s2+=v[i]*v[i]; }
  #pragma unroll
  for(int m=32;m>=1;m>>=1){ s += __shfl_xor(s,m); s2 += __shfl_xor(s2,m); }
  float mean = s*(1.f/DIMC);
  float var  = s2*(1.f/DIMC)-mean*mean;
  float rstd = rsqrtf(var+1e-5f);
  #pragma unroll
  for(int i=0;i<6;i++){
    int c = lane+i*64;
    xout[(size_t)row*DIMC+c] = f2bfu((v[i]-mean)*rstd*g[c]+bb[c]);
  }
}

extern "C" void kernel_launch(void* const* d_in, const int* in_sizes, int n_in,
                              void* d_out, int out_size, void* d_ws, size_t ws_size,
                              hipStream_t stream)
{
  const float* x     = (const float*)d_in[0];
  const float* n1g   = (const float*)d_in[1];
  const float* n1b   = (const float*)d_in[2];
  const float* apw   = (const float*)d_in[3];
  const float* apb   = (const float*)d_in[4];
  const float* n2g   = (const float*)d_in[5];
  const float* n2b   = (const float*)d_in[6];
  const float* inw   = (const float*)d_in[7];
  const float* inb   = (const float*)d_in[8];
  const float* convw = (const float*)d_in[9];
  const float* convb = (const float*)d_in[10];
  const float* xpw   = (const float*)d_in[11];
  const float* dtw   = (const float*)d_in[12];
  const float* dtb   = (const float*)d_in[13];
  const float* Alog  = (const float*)d_in[14];
  const float* Dp    = (const float*)d_in[15];
  const float* outw  = (const float*)d_in[16];
  const float* outb  = (const float*)d_in[17];
  const float* modw1 = (const float*)d_in[18];
  const float* modb1 = (const float*)d_in[19];
  const float* modw2 = (const float*)d_in[20];
  const float* modb2 = (const float*)d_in[21];
  const float* n3g   = (const float*)d_in[22];
  const float* n3b   = (const float*)d_in[23];
  const float* fc1w  = (const float*)d_in[24];
  const float* fc1b  = (const float*)d_in[25];
  const float* fc2w  = (const float*)d_in[26];
  const float* fc2b  = (const float*)d_in[27];

  // ---- workspace layout (f32 slots), total ~30.95M f = 123.8 MB ----
  float* ws = (float*)d_ws;
  float* XS    = ws;                       // 7,077,888 f
  float* R1    = ws + 7077888;             // 14,155,776 f multi-use region
  u16*   XMb   = (u16*)R1;
  u16*   DTb   = (u16*)R1;
  float* SSUM  = R1 + 7077888;             // 393,216 f
  float* HL    = R1 + 7471104;             // 6,291,456 f
  u16*   F1b   = (u16*)R1;
  u16*   Zb    = (u16*)(ws + 21233664);    // 14,155,776 u16 (= 7,077,888 f)
  float* DBC   = ws + 28311552;            // 1,032,192 f
  float* WB    = ws + 29343744;            // bf16 weights, 1,081,344 f slots
  u16*   inw_b   = (u16*)WB;                     // 589,824 sh (frag-linear)
  u16*   xpw_pad = inw_b + 589824;               // 98,304 sh
  u16*   outw_b  = xpw_pad + 98304;              // 294,912 sh
  u16*   fc1w_b  = outw_b + 294912;              // 589,824 sh
  u16*   fc2w_b  = fc1w_b + 589824;              // 589,824 sh
  float* SCORES= ws + 30425088;            // 147,456 f
  float* MEANR = ws + 30590976;            // 18,432
  float* RSTDR = ws + 30609408;            // 18,432
  float* GC    = ws + 30627840;            // 3,072
  float* MODH  = ws + 30630912;            // 6,144
  float* MOD   = ws + 30637056;            // 3,072
  u16*   DT32b = (u16*)(ws + 30640128);    // 589,824 sh (M x 32 dt-input, K-pad)
  u16*   dtw_pad=(u16*)(ws + 30935040);    // 24,576 sh (frag-linear 768x32)
  (void)ws_size; (void)n_in; (void)in_sizes; (void)out_size;

  // d_out as scratch: XN2b bf16 -> Ub bf16 -> Y bf16 (in-place over Ub) -> Hb bf16
  u16* XN2b = (u16*)d_out;
  u16* Ub   = (u16*)d_out;
  u16* Hb   = (u16*)d_out;

  // fused weight conversion (frag-linear swizzle) + GC zero
  k_cvtall<<<(OEND+255)/256, 256, 0, stream>>>(inw, xpw, outw, fc1w, fc2w, dtw,
      inw_b, xpw_pad, outw_b, fc1w_b, fc2w_b, dtw_pad, GC);

  k_transpose<<<dim3(72,12,8), dim3(32,8), 0, stream>>>(x, XS);
  k_lnstats<<<MROWS, 64, 0, stream>>>(XS, n1g,n1b,n2g,n2b, apw,apb, MEANR, RSTDR, XN2b, SCORES);
  k_softmax_L<<<BB*NHD, 256, 0, stream>>>(SCORES);
  k_gc<<<dim3(BB,48), 384, 0, stream>>>(SCORES, XS, MEANR, RSTDR, n1g, n1b, GC);
  k_mod1<<<dim3(BB,12), 256, 0, stream>>>(GC, modw1, modb1, MODH);
  k_mod2<<<dim3(BB,6), 256, 0, stream>>>(MODH, modw2, modb2, MOD);

  // in_proj fused: [XMb | Zb] = XN2 @ inw^T + inb   (K=384, N=1536, split store)
  k_mgemm<5><<<dim3(144,12), 256, 0, stream>>>(XN2b, inw_b, inb, XMb, 384, 1536, nullptr, Zb);
  // conv + silu -> Ub (bf16, in d_out; XN2b dead)
  k_conv<<<(MROWS*(DINN/8)+255)/256, 256, 0, stream>>>(XMb, convw, convb, Ub);
  // dbc = u @ xp_w^T (K=768): f32 DBC (col<56) + bf16 K-padded dt-input DT32b
  k_mgemm<6><<<dim3(144,1), 256, 0, stream>>>(Ub, xpw_pad, nullptr, DBC, 768, 56, nullptr, DT32b);
  // delta = softplus(DT32 @ dtw_pad^T + dtb) -> DTb bf16 (over dead XMb), K=32 MFMA
  k_mgemm<7><<<dim3(144,6), 256, 0, stream>>>(DT32b, dtw_pad, dtb, DTb, 32, 768, nullptr, nullptr);
  // chunked scan (d-per-thread, A-structure fast path)
  k_scan1<<<BB*NCH*3, 256, 0, stream>>>(DTb, Ub, DBC, Alog, SSUM, HL);
  k_scan2<<<384, 256, 0, stream>>>(SSUM, Alog, HL);
  k_scan3<<<BB*NCH*3, 256, 0, stream>>>(DTb, Ub, Zb, DBC, Alog, Dp, HL);
  // XS += (y @ out_w^T + out_b) * (1 + mod)   (K=768, N=384); Y lives in Ub slot
  k_mgemm<2><<<dim3(144,3), 256, 0, stream>>>(Ub, outw_b, outb, XS, 768, 384, MOD, nullptr);
  // Hb = LN3(XS)  (bf16, into d_out; Y dead)
  k_ln3<<<MROWS, 64, 0, stream>>>(XS, n3g, n3b, Hb);
  // F1b = gelu(H @ fc1_w^T + fc1_b)   (K=384, N=1536; overlays R1)
  k_mgemm<1><<<dim3(144,12), 256, 0, stream>>>(Hb, fc1w_b, fc1b, F1b, 384, 1536, nullptr, nullptr);
  // d_out = transpose(XS + F1 @ fc2_w^T + fc2_b)   (K=1536, N=384)
  k_mgemm<3><<<dim3(144,3), 256, 0, stream>>>(F1b, fc2w_b, fc2b, d_out, 1536, 384, XS, nullptr);
}

// Round 10
// 490.097 us; speedup vs baseline: 1.1333x; 1.0173x over previous
//
#include <hip/hip_runtime.h>
#include <math.h>

#define DIMC 384
#define NHD 8
#define NSTATE 16
#define DINN 768
#define DTRK 24
#define BB 8
#define LSEQ 2304
#define MROWS (BB*LSEQ)   // 18432
#define NCH 64
#define TCH 36            // LSEQ / NCH
#define L2E 1.44269504f

typedef unsigned short u16;
typedef short bf16x8 __attribute__((ext_vector_type(8)));
typedef float f32x4 __attribute__((ext_vector_type(4)));

__device__ __forceinline__ float sigmoid_(float x){ return 1.f/(1.f+__expf(-x)); }
__device__ __forceinline__ float silu_(float x){ return x*sigmoid_(x); }
__device__ __forceinline__ float softplus_(float x){ return (x>20.f)?x:log1pf(__expf(x)); }
__device__ __forceinline__ float gelu_(float x){
  float x3=x*x*x;
  return 0.5f*x*(1.f+tanhf(0.7978845608028654f*(x+0.044715f*x3)));
}
__device__ __forceinline__ float bfu2f(u16 u){
  union{unsigned int i; float f;} c; c.i=((unsigned int)u)<<16; return c.f;
}
__device__ __forceinline__ u16 f2bfu(float f){
  union{float f; unsigned int i;} c; c.f=f;
  unsigned int r = c.i + 0x7FFFu + ((c.i>>16)&1u);
  return (u16)(r>>16);
}
// async global->LDS, 16B per lane; dest must be wave-uniform base + lane*16
__device__ __forceinline__ void gl_lds16(const u16* g, u16* l){
  __builtin_amdgcn_global_load_lds((__attribute__((address_space(1))) void*)g,
      (__attribute__((address_space(3))) void*)l, 16, 0, 0);
}

// ---- weight f32 -> bf16, swizzled to MFMA-fragment-linear layout ----
// Wf[(nt*KT + kt)*512 + l*8 + e] = W[nt*16 + (l&15)][kt*32 + (l>>4)*8 + e]
__device__ __forceinline__ u16 swzw(const float* __restrict__ s, int o, int KT,
                                    int Nsrc, int Ksrc){
  int e = o&7, l = (o>>3)&63, rest = o>>9;
  int kt = rest % KT, nt = rest / KT;
  int n = nt*16 + (l&15);
  int k = kt*32 + ((l>>4)<<3) + e;
  return (n<Nsrc && k<Ksrc) ? f2bfu(s[(size_t)n*Ksrc + k]) : (u16)0;
}

#define O1 589824
#define O2 688128
#define O3 983040
#define O4 1572864
#define O5 2162688
#define O6 2187264
#define OEND 2190336
__global__ void k_cvtall(const float* __restrict__ inw, const float* __restrict__ xpw,
    const float* __restrict__ outw, const float* __restrict__ fc1w,
    const float* __restrict__ fc2w, const float* __restrict__ dtw,
    u16* __restrict__ inw_b, u16* __restrict__ xpw_pad, u16* __restrict__ outw_b,
    u16* __restrict__ fc1w_b, u16* __restrict__ fc2w_b, u16* __restrict__ dtw_pad,
    float* __restrict__ gc){
  int i = blockIdx.x*256+threadIdx.x;
  if(i >= OEND) return;
  if(i < O1){ inw_b[i]   = swzw(inw,  i,    12, 1536, 384); }
  else if(i < O2){ xpw_pad[i-O1] = swzw(xpw,  i-O1, 24, 56,   768); }
  else if(i < O3){ outw_b[i-O2]  = swzw(outw, i-O2, 24, 384,  768); }
  else if(i < O4){ fc1w_b[i-O3]  = swzw(fc1w, i-O3, 12, 1536, 384); }
  else if(i < O5){ fc2w_b[i-O4]  = swzw(fc2w, i-O4, 48, 384,  1536); }
  else if(i < O6){ dtw_pad[i-O5] = swzw(dtw,  i-O5, 1,  768,  24); }
  else { gc[i-O6]=0.f; }
}

// ---------------- transpose (B,C,L) -> (B,L,C) ----------------
__global__ void k_transpose(const float* __restrict__ x, float* __restrict__ xs){
  __shared__ float tile[32][33];
  int b = blockIdx.z;
  int t0 = blockIdx.x*32, c0 = blockIdx.y*32;
  int tx = threadIdx.x, ty = threadIdx.y; // 32 x 8
  const float* xb = x + (size_t)b*DIMC*LSEQ;
  #pragma unroll
  for(int q=0;q<4;q++)
    tile[ty+q*8][tx] = xb[(size_t)(c0+ty+q*8)*LSEQ + t0+tx];
  __syncthreads();
  float* xsb = xs + (size_t)b*LSEQ*DIMC;
  #pragma unroll
  for(int q=0;q<4;q++)
    xsb[(size_t)(t0+ty+q*8)*DIMC + c0+tx] = tile[tx][ty+q*8];
}

// -------- LN stats + LN2 (bf16 out) + attention scores --------
__global__ __launch_bounds__(64) void k_lnstats(const float* __restrict__ xs,
   const float* __restrict__ g1,const float* __restrict__ b1,
   const float* __restrict__ g2,const float* __restrict__ b2,
   const float* __restrict__ apw,const float* __restrict__ apb,
   float* __restrict__ meanr, float* __restrict__ rstdr,
   u16* __restrict__ xn2, float* __restrict__ scores){
  int row = blockIdx.x;
  int lane = threadIdx.x;
  const float* xr = xs + (size_t)row*DIMC;
  float v[6];
  float s=0.f, s2=0.f;
  #pragma unroll
  for(int i=0;i<6;i++){ v[i]=xr[lane+i*64]; s+=v[i]; s2+=v[i]*v[i]; }
  #pragma unroll
  for(int m=32;m>=1;m>>=1){ s += __shfl_xor(s,m); s2 += __shfl_xor(s2,m); }
  float mean = s*(1.f/DIMC);
  float var  = s2*(1.f/DIMC)-mean*mean;
  float rstd = rsqrtf(var+1e-5f);
  if(lane==0){ meanr[row]=mean; rstdr[row]=rstd; }
  float xv1[6];
  #pragma unroll
  for(int i=0;i<6;i++){
    int c = lane+i*64;
    float nx = (v[i]-mean)*rstd;
    xv1[i] = nx*g1[c]+b1[c];
    xn2[(size_t)row*DIMC+c] = f2bfu(nx*g2[c]+b2[c]);
  }
  #pragma unroll
  for(int h=0;h<NHD;h++){
    float p=0.f;
    #pragma unroll
    for(int i=0;i<6;i++) p += xv1[i]*apw[h*DIMC+lane+i*64];
    #pragma unroll
    for(int m=32;m>=1;m>>=1) p += __shfl_xor(p,m);
    if(lane==0) scores[(size_t)row*NHD+h]=p+apb[h];
  }
}

// ---------------- softmax over L per (b,h), in-place ----------------
__global__ __launch_bounds__(256) void k_softmax_L(float* __restrict__ sc){
  int bh = blockIdx.x; int b = bh>>3, h = bh&7;
  int tid = threadIdx.x;
  __shared__ float red[8];
  const size_t base = (size_t)b*LSEQ*NHD + h;
  float mx = -1e30f;
  for(int l=tid;l<LSEQ;l+=256) mx = fmaxf(mx, sc[base + (size_t)l*NHD]);
  #pragma unroll
  for(int m=32;m>=1;m>>=1) mx = fmaxf(mx, __shfl_xor(mx,m));
  if((tid&63)==0) red[tid>>6]=mx;
  __syncthreads();
  mx = fmaxf(fmaxf(red[0],red[1]),fmaxf(red[2],red[3]));
  float sum=0.f;
  for(int l=tid;l<LSEQ;l+=256) sum += __expf(sc[base+(size_t)l*NHD]-mx);
  #pragma unroll
  for(int m=32;m>=1;m>>=1) sum += __shfl_xor(sum,m);
  if((tid&63)==0) red[4+(tid>>6)]=sum;
  __syncthreads();
  float inv = 1.f/(red[4]+red[5]+red[6]+red[7]);
  for(int l=tid;l<LSEQ;l+=256){
    size_t idx = base+(size_t)l*NHD;
    sc[idx] = __expf(sc[idx]-mx)*inv;
  }
}

// gc[b,c] = sum_l mean_h(attn[b,l,h]) * xn1[b,l,c]  (xn1 recomputed, wpool inline)
__global__ __launch_bounds__(384) void k_gc(const float* __restrict__ attn,
    const float* __restrict__ xs, const float* __restrict__ meanr,
    const float* __restrict__ rstdr, const float* __restrict__ g1,
    const float* __restrict__ b1, float* __restrict__ gc){
  int b = blockIdx.x; int chunk = blockIdx.y; int c = threadIdx.x;
  int l0 = chunk*48;
  float acc=0.f, accw=0.f;
  for(int l=0;l<48;l++){
    int row = b*LSEQ + l0+l;
    const float* a = attn + (size_t)row*NHD;
    float ww = (((a[0]+a[1])+(a[2]+a[3]))+((a[4]+a[5])+(a[6]+a[7])))*0.125f;
    acc  += ww*(xs[(size_t)row*DIMC+c]-meanr[row])*rstdr[row];
    accw += ww;
  }
  atomicAdd(&gc[b*DIMC+c], acc*g1[c]+accw*b1[c]);
}

// mod MLP stage 1: MODH[b,n] = silu(gc[b,:]@w1[n,:]+b1[n]); 4 threads/output
__global__ __launch_bounds__(256) void k_mod1(const float* __restrict__ gc,
    const float* __restrict__ w1, const float* __restrict__ b1,
    float* __restrict__ modh){
  int b = blockIdx.x; int n = blockIdx.y*64 + (threadIdx.x>>2);
  int sub = threadIdx.x&3;
  const float4* g = (const float4*)(gc + b*DIMC) + sub*24;
  const float4* wr = (const float4*)(w1 + (size_t)n*DIMC) + sub*24;
  float acc=0.f;
  #pragma unroll
  for(int k=0;k<24;k++){
    float4 a=g[k], w=wr[k];
    acc += a.x*w.x + a.y*w.y + a.z*w.z + a.w*w.w;
  }
  acc += __shfl_xor(acc,1); acc += __shfl_xor(acc,2);
  if(sub==0) modh[b*768+n] = silu_(acc+b1[n]);
}
// mod MLP stage 2: MOD[b,n] = modh[b,:]@w2[n,:]+b2[n]; 4 threads/output
__global__ __launch_bounds__(256) void k_mod2(const float* __restrict__ modh,
    const float* __restrict__ w2, const float* __restrict__ b2,
    float* __restrict__ mod){
  int b = blockIdx.x; int n = blockIdx.y*64 + (threadIdx.x>>2);
  int sub = threadIdx.x&3;
  const float4* g = (const float4*)(modh + b*768) + sub*48;
  const float4* wr = (const float4*)(w2 + (size_t)n*768) + sub*48;
  float acc=0.f;
  #pragma unroll
  for(int k=0;k<48;k++){
    float4 a=g[k], w=wr[k];
    acc += a.x*w.x + a.y*w.y + a.z*w.z + a.w*w.w;
  }
  acc += __shfl_xor(acc,1); acc += __shfl_xor(acc,2);
  if(sub==0) mod[b*DIMC+n] = acc+b2[n];
}

// ======  bf16 MFMA GEMM, K templated: A via LDS (2-deep, counted vmcnt),
// B via frag-linear weights prefetched 1 iter ahead into registers.  ======
// Queue discipline per steady iter kt: issue B(kt+1)[4] -> vmcnt(6) retires
// A(kt)[2]+B(kt)[4] -> barrier -> ds_read A -> lgkm(0) -> barrier ->
// stage A(kt+2)[2] into just-read buffer -> 16 MFMA.  First iter vmcnt(4),
// last vmcnt(0).  All KT in use are even (12,24,48) or 1.
#define MG_STEP(KT_I, CUR, BIN, BOUT, VMSTR)                                   \
  {                                                                            \
    if((KT_I)+1 < KT){                                                         \
      _Pragma("unroll")                                                        \
      for(int j=0;j<4;j++)                                                     \
        BOUT[j] = *reinterpret_cast<const bf16x8*>(wp + 512 + j*(KT*512));     \
    }                                                                          \
    asm volatile("s_waitcnt " VMSTR ::: "memory");                             \
    __builtin_amdgcn_s_barrier();                                              \
    bf16x8 af[4];                                                              \
    {                                                                          \
      const u16* lbase = &lA[CUR][lofs];                                       \
      _Pragma("unroll")                                                        \
      for(int i=0;i<4;i++)                                                     \
        af[i] = *reinterpret_cast<const bf16x8*>(lbase + i*128);               \
    }                                                                          \
    asm volatile("s_waitcnt lgkmcnt(0)" ::: "memory");                         \
    __builtin_amdgcn_s_barrier();                                              \
    if((KT_I)+2 < KT){                                                         \
      gl_lds16(Ag0 + ((KT_I)+2)*32,      (CUR)? ld1 : ld0);                    \
      gl_lds16(Ag0 + ((KT_I)+2)*32 + 16, (CUR)? hd1 : hd0);                    \
    }                                                                          \
    _Pragma("unroll")                                                          \
    for(int i=0;i<4;i++)                                                       \
      _Pragma("unroll")                                                        \
      for(int j=0;j<4;j++)                                                     \
        acc[i][j] = __builtin_amdgcn_mfma_f32_16x16x32_bf16(af[i], BIN[j],     \
                                                            acc[i][j], 0,0,0);\
    wp += 512;                                                                 \
  }

template<int EPI, int K>
__global__ __launch_bounds__(256,4) void k_mgemm(
    const u16* __restrict__ A, const u16* __restrict__ Wf,
    const float* __restrict__ bias, void* __restrict__ outp,
    int N, const float* __restrict__ aux, void* __restrict__ outp2)
{
  constexpr int KT = K/32;
  __shared__ u16 lA[2][4096];   // [buf][kc:4][row:128][8]  (8 KB each)
  int tid = threadIdx.x;
  int m0 = blockIdx.x*128, n0 = blockIdx.y*128;
  int wid = tid>>6, lane = tid&63;
  int wr = wid>>1, wc = wid&1;
  int lrow = lane&15, lk = lane>>4;
  f32x4 acc[4][4];
  #pragma unroll
  for(int i=0;i<4;i++)
    #pragma unroll
    for(int j=0;j<4;j++){ acc[i][j][0]=0.f; acc[i][j][1]=0.f; acc[i][j][2]=0.f; acc[i][j][3]=0.f; }

  int r0 = tid & 127, k0 = tid >> 7;
  const u16* Ag0 = A + (size_t)(m0+r0)*K + k0*8;          // Ag1 = Ag0+16
  const u16* wp  = Wf + ((size_t)((n0>>4) + wc*4)*KT)*512 + (size_t)lane*8;
  const int lofs = (lk*128 + wr*64 + lrow)*8;
  u16* ld0 = &lA[0][tid*8];  u16* hd0 = &lA[0][2048+tid*8];
  u16* ld1 = &lA[1][tid*8];  u16* hd1 = &lA[1][2048+tid*8];

  // prologue: stage A(0) buf0, A(1) buf1; load B(0) regs
  gl_lds16(Ag0,    ld0);
  gl_lds16(Ag0+16, hd0);
  if(KT>1){
    gl_lds16(Ag0+32, ld1);
    gl_lds16(Ag0+48, hd1);
  }
  bf16x8 bA[4], bB[4];
  #pragma unroll
  for(int j=0;j<4;j++) bA[j] = *reinterpret_cast<const bf16x8*>(wp + j*(KT*512));

  if(KT==1){
    MG_STEP(0, 0, bA, bB, "vmcnt(0)")
  } else {
    MG_STEP(0, 0, bA, bB, "vmcnt(4)")
    for(int kt=1; kt<KT-1; kt+=2){
      MG_STEP(kt,   1, bB, bA, "vmcnt(6)")
      MG_STEP(kt+1, 0, bA, bB, "vmcnt(6)")
    }
    MG_STEP(KT-1, 1, bB, bA, "vmcnt(0)")
  }

  #pragma unroll
  for(int i=0;i<4;i++){
    int row = m0 + wr*64 + i*16 + lk*4;
    #pragma unroll
    for(int j=0;j<4;j++){
      int col = n0 + wc*64 + j*16 + lrow;
      float bc = bias ? bias[col] : 0.f;
      f32x4 v = acc[i][j];
      if(EPI==0){
        u16* o = (u16*)outp;
        #pragma unroll
        for(int r=0;r<4;r++) o[(size_t)(row+r)*N + col] = f2bfu(v[r]+bc);
      } else if(EPI==1){
        u16* o = (u16*)outp;
        #pragma unroll
        for(int r=0;r<4;r++) o[(size_t)(row+r)*N + col] = f2bfu(gelu_(v[r]+bc));
      } else if(EPI==2){
        float* o = (float*)outp;
        int bi = row/LSEQ;
        float sc = 1.f + aux[bi*DIMC + col];
        #pragma unroll
        for(int r=0;r<4;r++) o[(size_t)(row+r)*DIMC + col] += (v[r]+bc)*sc;
      } else if(EPI==3){
        float* o = (float*)outp;
        int bi = row/LSEQ, t = row - bi*LSEQ;
        float4 s;
        s.x = aux[(size_t)(row+0)*DIMC+col] + v[0] + bc;
        s.y = aux[(size_t)(row+1)*DIMC+col] + v[1] + bc;
        s.z = aux[(size_t)(row+2)*DIMC+col] + v[2] + bc;
        s.w = aux[(size_t)(row+3)*DIMC+col] + v[3] + bc;
        *reinterpret_cast<float4*>(&o[((size_t)(bi*DIMC+col))*LSEQ + t]) = s;
      } else if(EPI==4){
        float* o = (float*)outp;
        if(col < N){
          #pragma unroll
          for(int r=0;r<4;r++) o[(size_t)(row+r)*N + col] = v[r]+bc;
        }
      } else if(EPI==5){ // split into two (M,768) bf16 outputs
        u16* o = (col < 768) ? (u16*)outp : (u16*)outp2;
        int cc = (col < 768) ? col : col - 768;
        #pragma unroll
        for(int r=0;r<4;r++) o[(size_t)(row+r)*768 + cc] = f2bfu(v[r]+bc);
      } else if(EPI==6){ // dbc f32 (col<56) + dt-input bf16 K-padded to 32
        float* o = (float*)outp;
        u16* o2 = (u16*)outp2;
        #pragma unroll
        for(int r=0;r<4;r++){
          float val = v[r];
          if(col < 56) o[(size_t)(row+r)*56 + col] = val;
          if(col < 32) o2[(size_t)(row+r)*32 + col] = (col<DTRK)? f2bfu(val) : (u16)0;
        }
      } else { // EPI==7: softplus -> bf16
        u16* o = (u16*)outp;
        #pragma unroll
        for(int r=0;r<4;r++) o[(size_t)(row+r)*N + col] = f2bfu(softplus_(v[r]+bc));
      }
    }
  }
}

// ------- causal depthwise conv K=4 + silu, 8 channels/thread (bf16 in/out) -------
__global__ void k_conv(const u16* __restrict__ xm, const float* __restrict__ cw,
                       const float* __restrict__ cb, u16* __restrict__ u){
  int idx = blockIdx.x*256+threadIdx.x;
  if(idx >= MROWS*(DINN/8)) return;
  int j = idx % (DINN/8); int r = idx / (DINN/8);
  int t = r % LSEQ; int d0 = j*8;
  float4 w4_[8];
  #pragma unroll
  for(int e=0;e<8;e++) w4_[e] = reinterpret_cast<const float4*>(cw)[d0+e];
  float acc[8];
  #pragma unroll
  for(int e=0;e<8;e++) acc[e]=cb[d0+e];
  #pragma unroll
  for(int k=0;k<4;k++){
    int tt=t+k-3;
    if(tt>=0){
      uint4 v = *reinterpret_cast<const uint4*>(&xm[(size_t)(r+k-3)*DINN + d0]);
      unsigned vv[4]={v.x,v.y,v.z,v.w};
      #pragma unroll
      for(int e=0;e<8;e++){
        u16 raw = (e&1)? (u16)(vv[e>>1]>>16) : (u16)(vv[e>>1]&0xffffu);
        float wk = (k==0)? w4_[e].x : (k==1)? w4_[e].y : (k==2)? w4_[e].z : w4_[e].w;
        acc[e] += bfu2f(raw)*wk;
      }
    }
  }
  u16 outv[8];
  #pragma unroll
  for(int e=0;e<8;e++) outv[e]=f2bfu(silu_(acc[e]));
  *reinterpret_cast<uint4*>(&u[(size_t)r*DINN+d0]) = *reinterpret_cast<const uint4*>(outv);
}

// ============ chunked selective scan, d-per-thread ============
__global__ __launch_bounds__(256) void k_scan1(
  const u16* __restrict__ dt_, const u16* __restrict__ u_,
  const float* __restrict__ dbc, const float* __restrict__ alog,
  float* __restrict__ ssum, float* __restrict__ hloc)
{
  __shared__ float Bsh[TCH][16];
  int bid = blockIdx.x;
  int b = bid/(NCH*3); int rem = bid%(NCH*3); int ch = rem/3; int dblk = rem%3;
  int tid = threadIdx.x; int d = dblk*256 + tid;
  size_t rbase = (size_t)b*LSEQ + (size_t)ch*TCH;
  for(int j=tid; j<TCH*16; j+=256){
    int row=j>>4, n=j&15;
    Bsh[row][n] = dbc[(rbase+row)*56 + DTRK + n];
  }
  float Acl2[16];
  float a0 = -__expf(alog[(size_t)d*16])*L2E;
  bool fast = true;
  #pragma unroll
  for(int n=0;n<16;n++){
    Acl2[n] = -__expf(alog[(size_t)d*16+n])*L2E;
    float tgt = (float)(n+1)*a0;
    fast = fast && (fabsf(Acl2[n]-tgt) <= 1e-4f*fabsf(tgt));
  }
  float h[16];
  #pragma unroll
  for(int n=0;n<16;n++) h[n]=0.f;
  float S=0.f;
  const u16* dtp = dt_ + rbase*DINN + d;
  const u16* up  = u_  + rbase*DINN + d;
  __syncthreads();
  if(fast){
    for(int t=0;t<TCH;t++){
      float dt = bfu2f(dtp[(size_t)t*DINN]);
      float uv = bfu2f(up[(size_t)t*DINN]);
      float G = dt*uv;
      S += dt;
      float e = exp2f(dt*a0), w = e;
      const float4* b4 = (const float4*)Bsh[t];
      float4 B0=b4[0],B1=b4[1],B2=b4[2],B3=b4[3];
      float Bv[16]={B0.x,B0.y,B0.z,B0.w,B1.x,B1.y,B1.z,B1.w,
                    B2.x,B2.y,B2.z,B2.w,B3.x,B3.y,B3.z,B3.w};
      #pragma unroll
      for(int n=0;n<16;n++){ h[n] = h[n]*w + G*Bv[n]; w *= e; }
    }
  } else {
    for(int t=0;t<TCH;t++){
      float dt = bfu2f(dtp[(size_t)t*DINN]);
      float uv = bfu2f(up[(size_t)t*DINN]);
      float G = dt*uv;
      S += dt;
      const float4* b4 = (const float4*)Bsh[t];
      float4 B0=b4[0],B1=b4[1],B2=b4[2],B3=b4[3];
      float Bv[16]={B0.x,B0.y,B0.z,B0.w,B1.x,B1.y,B1.z,B1.w,
                    B2.x,B2.y,B2.z,B2.w,B3.x,B3.y,B3.z,B3.w};
      #pragma unroll
      for(int n=0;n<16;n++) h[n] = h[n]*exp2f(dt*Acl2[n]) + G*Bv[n];
    }
  }
  ssum[((size_t)b*NCH+ch)*DINN + d] = S;
  float* hp = hloc + (((size_t)b*NCH+ch)*DINN + d)*16;
  #pragma unroll
  for(int n=0;n<16;n++) hp[n] = h[n];
}

__global__ __launch_bounds__(256) void k_scan2(
  const float* __restrict__ ssum, const float* __restrict__ alog,
  float* __restrict__ hl)
{
  int gid = blockIdx.x*256+threadIdx.x;   // B*DINN*16
  int n = gid & 15; int d = (gid>>4)%DINN; int b = gid/(DINN*NSTATE);
  float Acl2 = -__expf(alog[(size_t)d*16+n])*L2E;
  float hin=0.f;
  for(int ch=0; ch<NCH; ch++){
    size_t sidx = ((size_t)b*NCH+ch)*DINN + d;
    size_t idx  = sidx*16 + n;
    float a = exp2f(ssum[sidx]*Acl2);
    float hold = hl[idx];
    hl[idx] = hin;
    hin = a*hin + hold;
  }
}

__global__ __launch_bounds__(256) void k_scan3(
  const u16* __restrict__ dt_, u16* uy, const u16* __restrict__ z_,
  const float* __restrict__ dbc, const float* __restrict__ alog,
  const float* __restrict__ Dp, const float* __restrict__ hin)
{
  __shared__ float BC[TCH][32];
  int bid = blockIdx.x;
  int b = bid/(NCH*3); int rem = bid%(NCH*3); int ch = rem/3; int dblk = rem%3;
  int tid = threadIdx.x; int d = dblk*256 + tid;
  size_t rbase = (size_t)b*LSEQ + (size_t)ch*TCH;
  for(int j=tid; j<TCH*32; j+=256){
    int row=j>>5, c=j&31;
    BC[row][c] = dbc[(rbase+row)*56 + DTRK + c];
  }
  float Acl2[16], h[16];
  const float* hp = hin + (((size_t)b*NCH+ch)*DINN + d)*16;
  float a0 = -__expf(alog[(size_t)d*16])*L2E;
  bool fast = true;
  #pragma unroll
  for(int n=0;n<16;n++){
    Acl2[n] = -__expf(alog[(size_t)d*16+n])*L2E;
    float tgt = (float)(n+1)*a0;
    fast = fast && (fabsf(Acl2[n]-tgt) <= 1e-4f*fabsf(tgt));
    h[n] = hp[n];
  }
  float Dv = Dp[d];
  const u16* dtp = dt_ + rbase*DINN + d;
  u16*       uyp = uy  + rbase*DINN + d;
  const u16* zp  = z_  + rbase*DINN + d;
  __syncthreads();
  if(fast){
    for(int t=0;t<TCH;t++){
      float dt = bfu2f(dtp[(size_t)t*DINN]);
      float uv = bfu2f(uyp[(size_t)t*DINN]);
      float zv = bfu2f(zp[(size_t)t*DINN]);
      float G = dt*uv;
      float e = exp2f(dt*a0), w = e;
      const float4* bc4 = (const float4*)BC[t];
      float4 B0=bc4[0],B1=bc4[1],B2=bc4[2],B3=bc4[3];
      float4 C0=bc4[4],C1=bc4[5],C2=bc4[6],C3=bc4[7];
      float Bv[16]={B0.x,B0.y,B0.z,B0.w,B1.x,B1.y,B1.z,B1.w,
                    B2.x,B2.y,B2.z,B2.w,B3.x,B3.y,B3.z,B3.w};
      float Cv[16]={C0.x,C0.y,C0.z,C0.w,C1.x,C1.y,C1.z,C1.w,
                    C2.x,C2.y,C2.z,C2.w,C3.x,C3.y,C3.z,C3.w};
      float y0=0.f,y1=0.f,y2=0.f,y3=0.f;
      #pragma unroll
      for(int n=0;n<16;n++){
        h[n] = h[n]*w + G*Bv[n];
        w *= e;
        if((n&3)==0) y0 += h[n]*Cv[n];
        else if((n&3)==1) y1 += h[n]*Cv[n];
        else if((n&3)==2) y2 += h[n]*Cv[n];
        else y3 += h[n]*Cv[n];
      }
      float y = (y0+y1)+(y2+y3);
      uyp[(size_t)t*DINN] = f2bfu((y + uv*Dv)*silu_(zv));
    }
  } else {
    for(int t=0;t<TCH;t++){
      float dt = bfu2f(dtp[(size_t)t*DINN]);
      float uv = bfu2f(uyp[(size_t)t*DINN]);
      float zv = bfu2f(zp[(size_t)t*DINN]);
      float G = dt*uv;
      const float4* bc4 = (const float4*)BC[t];
      float4 B0=bc4[0],B1=bc4[1],B2=bc4[2],B3=bc4[3];
      float4 C0=bc4[4],C1=bc4[5],C2=bc4[6],C3=bc4[7];
      float Bv[16]={B0.x,B0.y,B0.z,B0.w,B1.x,B1.y,B1.z,B1.w,
                    B2.x,B2.y,B2.z,B2.w,B3.x,B3.y,B3.z,B3.w};
      float Cv[16]={C0.x,C0.y,C0.z,C0.w,C1.x,C1.y,C1.z,C1.w,
                    C2.x,C2.y,C2.z,C2.w,C3.x,C3.y,C3.z,C3.w};
      float y0=0.f,y1=0.f,y2=0.f,y3=0.f;
      #pragma unroll
      for(int n=0;n<16;n++){
        h[n] = h[n]*exp2f(dt*Acl2[n]) + G*Bv[n];
        if((n&3)==0) y0 += h[n]*Cv[n];
        else if((n&3)==1) y1 += h[n]*Cv[n];
        else if((n&3)==2) y2 += h[n]*Cv[n];
        else y3 += h[n]*Cv[n];
      }
      float y = (y0+y1)+(y2+y3);
      uyp[(size_t)t*DINN] = f2bfu((y + uv*Dv)*silu_(zv));
    }
  }
}

// ---------------- LN3, bf16 out ----------------
__global__ __launch_bounds__(64) void k_ln3(const float* __restrict__ xin,
    const float* __restrict__ g, const float* __restrict__ bb, u16* __restrict__ xout){
  int row = blockIdx.x;
  int lane = threadIdx.x;
  const float* xr = xin + (size_t)row*DIMC;
  float v[6];
  float s=0.f, s2=0.f;
  #pragma unroll
  for(int i=0;i<6;i++){ v[i]=xr[lane+i*64]; s+=v[i]; s2+=v[i]*v[i]; }
  #pragma unroll
  for(int m=32;m>=1;m>>=1){ s += __shfl_xor(s,m); s2 += __shfl_xor(s2,m); }
  float mean = s*(1.f/DIMC);
  float var  = s2*(1.f/DIMC)-mean*mean;
  float rstd = rsqrtf(var+1e-5f);
  #pragma unroll
  for(int i=0;i<6;i++){
    int c = lane+i*64;
    xout[(size_t)row*DIMC+c] = f2bfu((v[i]-mean)*rstd*g[c]+bb[c]);
  }
}

extern "C" void kernel_launch(void* const* d_in, const int* in_sizes, int n_in,
                              void* d_out, int out_size, void* d_ws, size_t ws_size,
                              hipStream_t stream)
{
  const float* x     = (const float*)d_in[0];
  const float* n1g   = (const float*)d_in[1];
  const float* n1b   = (const float*)d_in[2];
  const float* apw   = (const float*)d_in[3];
  const float* apb   = (const float*)d_in[4];
  const float* n2g   = (const float*)d_in[5];
  const float* n2b   = (const float*)d_in[6];
  const float* inw   = (const float*)d_in[7];
  const float* inb   = (const float*)d_in[8];
  const float* convw = (const float*)d_in[9];
  const float* convb = (const float*)d_in[10];
  const float* xpw   = (const float*)d_in[11];
  const float* dtw   = (const float*)d_in[12];
  const float* dtb   = (const float*)d_in[13];
  const float* Alog  = (const float*)d_in[14];
  const float* Dp    = (const float*)d_in[15];
  const float* outw  = (const float*)d_in[16];
  const float* outb  = (const float*)d_in[17];
  const float* modw1 = (const float*)d_in[18];
  const float* modb1 = (const float*)d_in[19];
  const float* modw2 = (const float*)d_in[20];
  const float* modb2 = (const float*)d_in[21];
  const float* n3g   = (const float*)d_in[22];
  const float* n3b   = (const float*)d_in[23];
  const float* fc1w  = (const float*)d_in[24];
  const float* fc1b  = (const float*)d_in[25];
  const float* fc2w  = (const float*)d_in[26];
  const float* fc2b  = (const float*)d_in[27];

  // ---- workspace layout (f32 slots), total ~30.95M f = 123.8 MB ----
  float* ws = (float*)d_ws;
  float* XS    = ws;                       // 7,077,888 f
  float* R1    = ws + 7077888;             // 14,155,776 f multi-use region
  u16*   XMb   = (u16*)R1;
  u16*   DTb   = (u16*)R1;
  float* SSUM  = R1 + 7077888;             // 393,216 f
  float* HL    = R1 + 7471104;             // 6,291,456 f
  u16*   F1b   = (u16*)R1;
  u16*   Zb    = (u16*)(ws + 21233664);    // 14,155,776 u16 (= 7,077,888 f)
  float* DBC   = ws + 28311552;            // 1,032,192 f
  float* WB    = ws + 29343744;            // bf16 weights, 1,081,344 f slots
  u16*   inw_b   = (u16*)WB;                     // 589,824 sh (frag-linear)
  u16*   xpw_pad = inw_b + 589824;               // 98,304 sh
  u16*   outw_b  = xpw_pad + 98304;              // 294,912 sh
  u16*   fc1w_b  = outw_b + 294912;              // 589,824 sh
  u16*   fc2w_b  = fc1w_b + 589824;              // 589,824 sh
  float* SCORES= ws + 30425088;            // 147,456 f
  float* MEANR = ws + 30590976;            // 18,432
  float* RSTDR = ws + 30609408;            // 18,432
  float* GC    = ws + 30627840;            // 3,072
  float* MODH  = ws + 30630912;            // 6,144
  float* MOD   = ws + 30637056;            // 3,072
  u16*   DT32b = (u16*)(ws + 30640128);    // 589,824 sh (M x 32 dt-input, K-pad)
  u16*   dtw_pad=(u16*)(ws + 30935040);    // 24,576 sh (frag-linear 768x32)
  (void)ws_size; (void)n_in; (void)in_sizes; (void)out_size;

  // d_out as scratch: XN2b bf16 -> Ub bf16 -> Y bf16 (in-place over Ub) -> Hb bf16
  u16* XN2b = (u16*)d_out;
  u16* Ub   = (u16*)d_out;
  u16* Hb   = (u16*)d_out;

  // fused weight conversion (frag-linear swizzle) + GC zero
  k_cvtall<<<(OEND+255)/256, 256, 0, stream>>>(inw, xpw, outw, fc1w, fc2w, dtw,
      inw_b, xpw_pad, outw_b, fc1w_b, fc2w_b, dtw_pad, GC);

  k_transpose<<<dim3(72,12,8), dim3(32,8), 0, stream>>>(x, XS);
  k_lnstats<<<MROWS, 64, 0, stream>>>(XS, n1g,n1b,n2g,n2b, apw,apb, MEANR, RSTDR, XN2b, SCORES);
  k_softmax_L<<<BB*NHD, 256, 0, stream>>>(SCORES);
  k_gc<<<dim3(BB,48), 384, 0, stream>>>(SCORES, XS, MEANR, RSTDR, n1g, n1b, GC);
  k_mod1<<<dim3(BB,12), 256, 0, stream>>>(GC, modw1, modb1, MODH);
  k_mod2<<<dim3(BB,6), 256, 0, stream>>>(MODH, modw2, modb2, MOD);

  // in_proj fused: [XMb | Zb] = XN2 @ inw^T + inb   (K=384, N=1536, split store)
  k_mgemm<5,384><<<dim3(144,12), 256, 0, stream>>>(XN2b, inw_b, inb, XMb, 1536, nullptr, Zb);
  // conv + silu -> Ub (bf16, in d_out; XN2b dead)
  k_conv<<<(MROWS*(DINN/8)+255)/256, 256, 0, stream>>>(XMb, convw, convb, Ub);
  // dbc = u @ xp_w^T (K=768): f32 DBC (col<56) + bf16 K-padded dt-input DT32b
  k_mgemm<6,768><<<dim3(144,1), 256, 0, stream>>>(Ub, xpw_pad, nullptr, DBC, 56, nullptr, DT32b);
  // delta = softplus(DT32 @ dtw_pad^T + dtb) -> DTb bf16 (over dead XMb), K=32 MFMA
  k_mgemm<7,32><<<dim3(144,6), 256, 0, stream>>>(DT32b, dtw_pad, dtb, DTb, 768, nullptr, nullptr);
  // chunked scan (d-per-thread, A-structure fast path)
  k_scan1<<<BB*NCH*3, 256, 0, stream>>>(DTb, Ub, DBC, Alog, SSUM, HL);
  k_scan2<<<384, 256, 0, stream>>>(SSUM, Alog, HL);
  k_scan3<<<BB*NCH*3, 256, 0, stream>>>(DTb, Ub, Zb, DBC, Alog, Dp, HL);
  // XS += (y @ out_w^T + out_b) * (1 + mod)   (K=768, N=384); Y lives in Ub slot
  k_mgemm<2,768><<<dim3(144,3), 256, 0, stream>>>(Ub, outw_b, outb, XS, 384, MOD, nullptr);
  // Hb = LN3(XS)  (bf16, into d_out; Y dead)
  k_ln3<<<MROWS, 64, 0, stream>>>(XS, n3g, n3b, Hb);
  // F1b = gelu(H @ fc1_w^T + fc1_b)   (K=384, N=1536; overlays R1)
  k_mgemm<1,384><<<dim3(144,12), 256, 0, stream>>>(Hb, fc1w_b, fc1b, F1b, 1536, nullptr, nullptr);
  // d_out = transpose(XS + F1 @ fc2_w^T + fc2_b)   (K=1536, N=384)
  k_mgemm<3,1536><<<dim3(144,3), 256, 0, stream>>>(F1b, fc2w_b, fc2b, d_out, 384, XS, nullptr);
}